// Round 16
// baseline (502.588 us; speedup 1.0000x reference)
//
#include <hip/hip_runtime.h>

#define S_TOT 30285
#define SPAD  30720
#define EPS_S 3.0285e-4f  // 1e-8 * S_TOT

typedef __attribute__((ext_vector_type(8))) short bf16x8;
typedef __attribute__((ext_vector_type(4))) float f32x4;

__device__ __forceinline__ unsigned short f2bf(float f) {
  unsigned u = __float_as_uint(f);
  u += 0x7FFFu + ((u >> 16) & 1u);
  return (unsigned short)(u >> 16);
}
__device__ __forceinline__ float bf2f(unsigned short h) {
  return __uint_as_float(((unsigned)h) << 16);
}
__device__ __forceinline__ float allred_sum(float v) {
#pragma unroll
  for (int o = 32; o > 0; o >>= 1) v += __shfl_xor(v, o, 64);
  return v;
}
// ---- fp8 e4m3fn encode/decode (bit-exact, no header dependency) ----
__device__ __forceinline__ unsigned char fp8e(float f) {
  unsigned s = (__float_as_uint(f) >> 24) & 0x80u;
  float a = fminf(fabsf(f), 448.f);
  if (a < 0.015625f) {  // subnormal target (< 2^-6)
    int m = (int)rintf(a * 512.f);  // 0..8 (8 -> 0x08 == 2^-6, still correct)
    return (unsigned char)(s | (unsigned)m);
  }
  int e;
  float fr = frexpf(a, &e);          // a = fr*2^e, fr in [0.5,1)
  float mant = ldexpf(a, -(e - 1));  // [1,2)
  int m3 = (int)rintf((mant - 1.f) * 8.f);
  int E4 = e + 6;
  if (m3 == 8) { m3 = 0; E4++; }
  if (E4 > 15) { E4 = 15; m3 = 7; }
  return (unsigned char)(s | ((unsigned)E4 << 3) | (unsigned)m3);
}
__device__ __forceinline__ float fp8d(unsigned char b) {
  unsigned em = b & 0x7Fu;
  float mag = (em >= 8u) ? __uint_as_float((em + 960u) << 20)
                         : (float)em * 0.001953125f;  // em * 2^-9
  return __uint_as_float((((unsigned)b & 0x80u) << 24) | __float_as_uint(mag));
}

// ---------- fused prep: word_attn + wd + casts + transposes + slot init + zeroing ----------
__global__ void k_prep(const float* __restrict__ doc, const float* __restrict__ w_wa,
                       const float* __restrict__ b_wa, const float* __restrict__ wemb,
                       const float* __restrict__ wsp, const float* __restrict__ wk,
                       const float* __restrict__ wv, const float* __restrict__ wq,
                       const float* __restrict__ w1, const float* __restrict__ w2,
                       const float* __restrict__ wih, const float* __restrict__ whh,
                       const float* __restrict__ slots_q, float* __restrict__ wa,
                       float* __restrict__ Wd, unsigned short* __restrict__ docb,
                       unsigned short* __restrict__ wihb, unsigned short* __restrict__ whhb,
                       unsigned short* __restrict__ wspT, unsigned short* __restrict__ wkT,
                       unsigned short* __restrict__ wvT, unsigned short* __restrict__ wqT,
                       unsigned short* __restrict__ w1T, unsigned short* __restrict__ w2T,
                       unsigned char* __restrict__ wqF8, unsigned char* __restrict__ w1F8,
                       unsigned char* __restrict__ w2F8,
                       float* __restrict__ slots, float* __restrict__ zeroF,
                       unsigned short* __restrict__ inbpad) {
  __shared__ float shf[1056];
  int b = blockIdx.x, t = threadIdx.x;
  if (b < 1024) {  // word_attn
    float s = 0.f;
    for (int h = t; h < 1024; h += 256) s += doc[b * 1024 + h] * w_wa[h];
    shf[t] = s;
    __syncthreads();
    for (int o = 128; o; o >>= 1) {
      if (t < o) shf[t] += shf[t + o];
      __syncthreads();
    }
    if (t == 0) wa[b] = shf[0] + b_wa[0];
  } else if (b < 1054) {  // Wd
    int w = b - 1024;
    float s = 0.f;
    for (int j = 0; j < 20; j++) s += wemb[w * 20 + j] * wsp[(2048 + j) * 256 + t];
    Wd[w * 256 + t] = s;
  } else if (b < 6686) {  // row-major casts
    int b2 = b - 1054;
    if (b2 < 4096) { int i = b2 * 256 + t; docb[i] = f2bf(doc[i]); }
    else if (b2 < 4864) { int i = (b2 - 4096) * 256 + t; wihb[i] = f2bf(wih[i]); }
    else { int i = (b2 - 4864) * 256 + t; whhb[i] = f2bf(whh[i]); }
  } else if (b < 7902) {  // transposed casts (bf16 always; fp8 additionally for wq/w1/w2)
    int bb = b - 6686;
    const float* src; unsigned short* dst; unsigned char* dst8 = nullptr; int R, C, tid;
    if (bb < 768) {
      int sec = bb >> 8; tid = bb & 255;
      src = wsp + (sec == 0 ? 0 : (sec == 1 ? 1024 * 256 : 2068 * 256));
      dst = wspT + (size_t)sec * 256 * 1024; R = 1024; C = 256;
    } else if (bb < 832) { src = wk; dst = wkT; R = 256; C = 256; tid = bb - 768; }
    else if (bb < 896) { src = wv; dst = wvT; R = 256; C = 256; tid = bb - 832; }
    else if (bb < 960) { src = wq; dst = wqT; dst8 = wqF8; R = 256; C = 256; tid = bb - 896; }
    else if (bb < 1088) { src = w1; dst = w1T; dst8 = w1F8; R = 256; C = 512; tid = bb - 960; }
    else { src = w2; dst = w2T; dst8 = w2F8; R = 512; C = 256; tid = bb - 1088; }
    int cw = C >> 5;
    int c0 = (tid % cw) * 32, r0 = (tid / cw) * 32;
#pragma unroll
    for (int i = 0; i < 4; i++) {
      int e = i * 256 + t, rr = e >> 5, cc = e & 31;
      shf[rr * 33 + cc] = src[(size_t)(r0 + rr) * C + c0 + cc];
    }
    __syncthreads();
#pragma unroll
    for (int i = 0; i < 4; i++) {
      int e = i * 256 + t, cc = e >> 5, rr = e & 31;
      float v = shf[rr * 33 + cc];
      size_t idx = (size_t)(c0 + cc) * R + r0 + rr;
      dst[idx] = f2bf(v);
      if (dst8) dst8[idx] = fp8e(v);
    }
  } else if (b < 7909) {  // slots init (rows 0..99 copy, 100..111 zero)
    int r0 = (b - 7902) * 16;
    for (int rr = 0; rr < 16; rr++) {
      int row = r0 + rr;
      slots[row * 256 + t] = (row < 100) ? slots_q[row * 256 + t] : 0.f;
    }
  } else if (b < 7994) {  // zero f32 region: vsum(256) + rowsum(384) + uraw(86016)
    int i4 = (b - 7909) * 256 + t;
    if (i4 < 21664) ((float4*)zeroF)[i4] = (float4){0.f, 0.f, 0.f, 0.f};
  } else {  // zero inb padding rows (bf16)
    int i = (b - 7994) * 256 + t;
    if (i < 13920) ((uint4*)inbpad)[i] = (uint4){0u, 0u, 0u, 0u};
  }
}

// ---------- A/B/C projections (MFMA) ----------
__global__ __launch_bounds__(256) void k_abc_mfma(const unsigned short* __restrict__ docb,
                                                  const unsigned short* __restrict__ wspT,
                                                  float* __restrict__ A, float* __restrict__ B,
                                                  float* __restrict__ C) {
  int rt = blockIdx.x, sec = blockIdx.y;
  float* out = sec == 0 ? A : (sec == 1 ? B : C);
  const unsigned short* wt = wspT + (size_t)sec * 256 * 1024;
  __shared__ unsigned short lds[64 * 256];
  int t = threadIdx.x, w = t >> 6, l = t & 63, lr = l & 15, lh = l >> 4;
  f32x4 acc[4][4];
#pragma unroll
  for (int m = 0; m < 4; m++)
#pragma unroll
    for (int n = 0; n < 4; n++) acc[m][n] = (f32x4){0.f, 0.f, 0.f, 0.f};
  for (int kt = 0; kt < 4; kt++) {
    __syncthreads();
#pragma unroll
    for (int it = 0; it < 8; it++) {
      int e = it * 256 + t, row = e >> 5, c16 = e & 31;
      int ba = ((row * 512) + c16 * 16) ^ ((row & 7) << 4);
      *(uint4*)((char*)lds + ba) =
          *(const uint4*)(docb + (size_t)(rt * 64 + row) * 1024 + kt * 256 + c16 * 8);
    }
    __syncthreads();
    for (int kk = 0; kk < 8; kk++) {
      bf16x8 afr[4];
#pragma unroll
      for (int m = 0; m < 4; m++) {
        int row = m * 16 + lr;
        int ba = ((row * 512) + kk * 64 + lh * 16) ^ ((row & 7) << 4);
        afr[m] = *(bf16x8*)((char*)lds + ba);
      }
#pragma unroll
      for (int n = 0; n < 4; n++) {
        bf16x8 b8 = *(const bf16x8*)(wt + (size_t)(w * 64 + n * 16 + lr) * 1024 + kt * 256 +
                                     kk * 32 + lh * 8);
#pragma unroll
        for (int m = 0; m < 4; m++)
          acc[m][n] = __builtin_amdgcn_mfma_f32_16x16x32_bf16(afr[m], b8, acc[m][n], 0, 0, 0);
      }
    }
  }
#pragma unroll
  for (int n = 0; n < 4; n++) {
    int col = w * 64 + n * 16 + lr;
#pragma unroll
    for (int m = 0; m < 4; m++)
#pragma unroll
      for (int r = 0; r < 4; r++)
        out[(size_t)(rt * 64 + m * 16 + lh * 4 + r) * 256 + col] = acc[m][n][r];
  }
}

// ---------- spans: wave-parallel online-softmax + fused LN; no in-loop barriers ----------
__global__ void k_spans_ln(const float* __restrict__ wa, const float* __restrict__ A,
                           const float* __restrict__ B, const float* __restrict__ C,
                           const float* __restrict__ Wd, const float* __restrict__ bias,
                           const float* __restrict__ g_in, const float* __restrict__ be_in,
                           float* __restrict__ xin, unsigned short* __restrict__ inb) {
  int ss = blockIdx.x, t = threadIdx.x;
  int w = t >> 6, lane = t & 63;
  int nsp = min(30, 1024 - ss);
  int base = (ss < 995) ? ss * 30 : 29850 + 435 - ((1024 - ss) * (1025 - ss)) / 2;
  __shared__ float C_l[30 * 256];
  __shared__ float wa_l[30];
  for (int e = t; e < nsp * 256; e += 256)
    C_l[e] = C[(ss + (e >> 8)) * 256 + (e & 255)];
  if (t < nsp) wa_l[t] = wa[ss + t];
  __syncthreads();
  int c0 = lane * 4;
  float4 aS = *(const float4*)(A + ss * 256 + c0);
  float4 bi = *(const float4*)(bias + c0);
  float a0 = aS.x + bi.x, a1 = aS.y + bi.y, a2 = aS.z + bi.z, a3 = aS.w + bi.w;
  float4 gg = *(const float4*)(g_in + c0);
  float4 bb = *(const float4*)(be_in + c0);
  float m = -3.4e38f, Z = 0.f;
  float W0 = 0.f, W1 = 0.f, W2 = 0.f, W3 = 0.f;
  int pos = 0;
  for (int sp = w; sp < nsp; sp += 4) {
    for (; pos <= sp; ++pos) {
      float as_ = wa_l[pos];
      float mn = fmaxf(m, as_);
      float corr = __expf(m - mn);
      float e = __expf(as_ - mn);
      Z = Z * corr + e;
      float4 cc = *(const float4*)(C_l + pos * 256 + c0);
      W0 = W0 * corr + e * cc.x;
      W1 = W1 * corr + e * cc.y;
      W2 = W2 * corr + e * cc.z;
      W3 = W3 * corr + e * cc.w;
      m = mn;
    }
    float invZ = 1.f / Z;
    float4 Bv = *(const float4*)(B + (size_t)(ss + sp) * 256 + c0);
    float4 wd = *(const float4*)(Wd + sp * 256 + c0);
    float v0 = a0 + Bv.x + wd.x + W0 * invZ;
    float v1 = a1 + Bv.y + wd.y + W1 * invZ;
    float v2 = a2 + Bv.z + wd.z + W2 * invZ;
    float v3 = a3 + Bv.w + wd.w + W3 * invZ;
    float s = allred_sum(v0 + v1 + v2 + v3);
    float mean = s * (1.f / 256.f);
    float d0 = v0 - mean, d1 = v1 - mean, d2 = v2 - mean, d3 = v3 - mean;
    float q = allred_sum(d0 * d0 + d1 * d1 + d2 * d2 + d3 * d3);
    float rstd = rsqrtf(q * (1.f / 256.f) + 1e-5f);
    float o0 = d0 * rstd * gg.x + bb.x;
    float o1 = d1 * rstd * gg.y + bb.y;
    float o2 = d2 * rstd * gg.z + bb.z;
    float o3 = d3 * rstd * gg.w + bb.w;
    size_t r = (size_t)(base + sp) * 256 + c0;
    *(float4*)(xin + r) = (float4){o0, o1, o2, o3};
    ushort4 u4;
    u4.x = f2bf(o0); u4.y = f2bf(o1); u4.z = f2bf(o2); u4.w = f2bf(o3);
    *(ushort4*)(inb + r) = u4;
  }
}

// ---------- k/v projection MFMA; vsum fused ----------
__global__ __launch_bounds__(256) void k_kv_mfma(const unsigned short* __restrict__ inb,
                                                 const unsigned short* __restrict__ wkT,
                                                 const unsigned short* __restrict__ wvT,
                                                 const float* __restrict__ bk,
                                                 const float* __restrict__ bv,
                                                 unsigned short* __restrict__ kb,
                                                 unsigned short* __restrict__ vT,
                                                 float* __restrict__ vsum) {
  int j0 = blockIdx.x * 64;
  int t = threadIdx.x, w = t >> 6, l = t & 63, lr = l & 15, lh = l >> 4;
  __shared__ unsigned short lds[64 * 256];
#pragma unroll
  for (int it = 0; it < 8; it++) {
    int e = it * 256 + t, row = e >> 5, c16 = e & 31;
    int ba = ((row * 512) + c16 * 16) ^ ((row & 7) << 4);
    *(uint4*)((char*)lds + ba) = *(const uint4*)(inb + (size_t)(j0 + row) * 256 + c16 * 8);
  }
  __syncthreads();
  f32x4 ak[4][4], av[4][4];
#pragma unroll
  for (int m = 0; m < 4; m++)
#pragma unroll
    for (int n = 0; n < 4; n++) {
      ak[m][n] = (f32x4){0.f, 0.f, 0.f, 0.f};
      av[m][n] = (f32x4){0.f, 0.f, 0.f, 0.f};
    }
  for (int kk = 0; kk < 8; kk++) {
    bf16x8 afr[4];
#pragma unroll
    for (int m = 0; m < 4; m++) {
      int row = m * 16 + lr;
      int ba = ((row * 512) + kk * 64 + lh * 16) ^ ((row & 7) << 4);
      afr[m] = *(bf16x8*)((char*)lds + ba);
    }
#pragma unroll
    for (int n = 0; n < 4; n++) {
      int col = w * 64 + n * 16 + lr;
      bf16x8 bk8 = *(const bf16x8*)(wkT + (size_t)col * 256 + kk * 32 + lh * 8);
      bf16x8 bv8 = *(const bf16x8*)(wvT + (size_t)col * 256 + kk * 32 + lh * 8);
#pragma unroll
      for (int m = 0; m < 4; m++) {
        ak[m][n] = __builtin_amdgcn_mfma_f32_16x16x32_bf16(afr[m], bk8, ak[m][n], 0, 0, 0);
        av[m][n] = __builtin_amdgcn_mfma_f32_16x16x32_bf16(afr[m], bv8, av[m][n], 0, 0, 0);
      }
    }
  }
#pragma unroll
  for (int n = 0; n < 4; n++) {
    int col = w * 64 + n * 16 + lr;
    float bks = bk[col], bvs = bv[col];
    float cs = 0.f;
#pragma unroll
    for (int m = 0; m < 4; m++)
#pragma unroll
      for (int r = 0; r < 4; r++) {
        int row = j0 + m * 16 + lh * 4 + r;
        float kvv = ak[m][n][r] + bks;
        float vvv = av[m][n][r] + bvs;
        kb[(size_t)row * 256 + col] = f2bf(kvv);
        vT[(size_t)col * SPAD + row] = f2bf(vvv);
        if (row < S_TOT) cs += vvv;
      }
    cs += __shfl_xor(cs, 16, 64);
    cs += __shfl_xor(cs, 32, 64);
    if (lh == 0) atomicAdd(&vsum[col], cs);
  }
}

// ---------- initial q: q = LN(slots)@wq + bq (one block per slot row, VALU) ----------
__global__ void k_qln0(const float* __restrict__ slots, const float* __restrict__ g_sl,
                       const float* __restrict__ be_sl, const unsigned short* __restrict__ wqT,
                       const float* __restrict__ bq, unsigned short* __restrict__ qbf) {
  int i = blockIdx.x, t = threadIdx.x;
  if (i >= 100) { qbf[i * 256 + t] = 0; return; }
  __shared__ float ln_l[256];
  __shared__ float red[8];
  int wave = t >> 6, lane = t & 63;
  float v = slots[i * 256 + t];
  float s = allred_sum(v);
  if (lane == 0) red[wave] = s;
  __syncthreads();
  float mean = (red[0] + red[1] + red[2] + red[3]) * (1.f / 256.f);
  float dv = v - mean;
  float s2 = allred_sum(dv * dv);
  if (lane == 0) red[4 + wave] = s2;
  __syncthreads();
  float var = (red[4] + red[5] + red[6] + red[7]) * (1.f / 256.f);
  ln_l[t] = dv * rsqrtf(var + 1e-5f) * g_sl[t] + be_sl[t];
  __syncthreads();
  float q = bq[t];
  size_t c = (size_t)t * 256;
  for (int d = 0; d < 256; d += 8) {
    bf16x8 a = *(const bf16x8*)(wqT + c + d);
#pragma unroll
    for (int e = 0; e < 8; e++) q += bf2f((unsigned short)a[e]) * ln_l[d + e];
  }
  qbf[i * 256 + t] = f2bf(q);
}

// ---------- fused dots(MFMA) + slot-softmax + (pT/rowsum | coref) ----------
__global__ __launch_bounds__(256) void k_dots_f(const unsigned short* __restrict__ kb,
                                                const unsigned short* __restrict__ qb,
                                                unsigned short* __restrict__ pT,
                                                float* __restrict__ rowsum,
                                                float* __restrict__ coref, int final_, int S_) {
  int j0 = blockIdx.x * 64;
  int t = threadIdx.x, w = t >> 6, l = t & 63, lr = l & 15, lh = l >> 4;
  f32x4 acc[7];
#pragma unroll
  for (int n = 0; n < 7; n++) acc[n] = (f32x4){0.f, 0.f, 0.f, 0.f};
  const unsigned short* arow = kb + (size_t)(j0 + w * 16 + lr) * 256;
  for (int kk = 0; kk < 8; kk++) {
    bf16x8 a8 = *(const bf16x8*)(arow + kk * 32 + lh * 8);
#pragma unroll
    for (int n = 0; n < 7; n++) {
      bf16x8 b8 = *(const bf16x8*)(qb + (size_t)(n * 16 + lr) * 256 + kk * 32 + lh * 8);
      acc[n] = __builtin_amdgcn_mfma_f32_16x16x32_bf16(a8, b8, acc[n], 0, 0, 0);
    }
  }
  __shared__ float dt[64][117];
#pragma unroll
  for (int n = 0; n < 7; n++)
#pragma unroll
    for (int r = 0; r < 4; r++) dt[w * 16 + lh * 4 + r][n * 16 + lr] = acc[n][r] * 0.0625f;
  __syncthreads();
  int jj = t >> 2, q4 = t & 3;
  float mx = -3.4e38f;
#pragma unroll
  for (int i = 0; i < 25; i++) mx = fmaxf(mx, dt[jj][q4 * 25 + i]);
  mx = fmaxf(mx, __shfl_xor(mx, 1, 64));
  mx = fmaxf(mx, __shfl_xor(mx, 2, 64));
  float sm = 0.f;
#pragma unroll
  for (int i = 0; i < 25; i++) {
    float e = __expf(dt[jj][q4 * 25 + i] - mx);
    dt[jj][q4 * 25 + i] = e;
    sm += e;
  }
  sm += __shfl_xor(sm, 1, 64);
  sm += __shfl_xor(sm, 2, 64);
  float inv = 1.f / sm;
#pragma unroll
  for (int i = 0; i < 25; i++) dt[jj][q4 * 25 + i] *= inv;
  __syncthreads();
  if (!final_) {
    for (int e = t; e < 112 * 64; e += 256) {
      int i = e >> 6, j2 = e & 63;
      float pv = (i < 100 && (j0 + j2) < S_) ? dt[j2][i] : 0.f;
      pT[(size_t)i * SPAD + j0 + j2] = f2bf(pv);
    }
    int nv = S_ - j0;
    if (nv > 64) nv = 64;
    if (t < 100) {
      float s = 0.f;
      for (int j2 = 0; j2 < nv; j2++) s += dt[j2][t];
      atomicAdd(rowsum + t, s);
    }
  } else {
    for (int e = t; e < 100 * 64; e += 256) {
      int i = e >> 6, j2 = e & 63;
      if ((j0 + j2) < S_) coref[(size_t)i * S_ + j0 + j2] = fminf(dt[j2][i] + 1e-8f, 1.0f);
    }
  }
}

// ---------- updates: uraw += pT @ v (MFMA split-K atomics) ----------
__global__ __launch_bounds__(256) void k_upd_mfma(const unsigned short* __restrict__ pT,
                                                  const unsigned short* __restrict__ vT,
                                                  float* __restrict__ uraw) {
  int kc = blockIdx.x, ny = blockIdx.y;
  int t = threadIdx.x, w = t >> 6, l = t & 63, lr = l & 15, lh = l >> 4;
  int k0 = kc * 320;
  int c0 = ny * 128 + w * 32;
  f32x4 acc[7][2];
#pragma unroll
  for (int m = 0; m < 7; m++) {
    acc[m][0] = (f32x4){0.f, 0.f, 0.f, 0.f};
    acc[m][1] = (f32x4){0.f, 0.f, 0.f, 0.f};
  }
  for (int ks = 0; ks < 10; ks++) {
    int kof = k0 + ks * 32 + lh * 8;
    bf16x8 b0 = *(const bf16x8*)(vT + (size_t)(c0 + lr) * SPAD + kof);
    bf16x8 b1 = *(const bf16x8*)(vT + (size_t)(c0 + 16 + lr) * SPAD + kof);
#pragma unroll
    for (int m = 0; m < 7; m++) {
      bf16x8 a8 = *(const bf16x8*)(pT + (size_t)(m * 16 + lr) * SPAD + kof);
      acc[m][0] = __builtin_amdgcn_mfma_f32_16x16x32_bf16(a8, b0, acc[m][0], 0, 0, 0);
      acc[m][1] = __builtin_amdgcn_mfma_f32_16x16x32_bf16(a8, b1, acc[m][1], 0, 0, 0);
    }
  }
#pragma unroll
  for (int m = 0; m < 7; m++)
#pragma unroll
    for (int n = 0; n < 2; n++)
#pragma unroll
      for (int r = 0; r < 4; r++) {
        int i = m * 16 + lh * 4 + r;
        if (i < 100) atomicAdd(&uraw[i * 256 + c0 + n * 16 + lr], acc[m][n][r]);
      }
}

// ---------- gates GEMM (col-tiled, 24 blocks): gi/gh = {u,slots}@W^T + b ----------
__global__ __launch_bounds__(256) void k_gates(
    const float* __restrict__ uraw, const float* __restrict__ vsum,
    const float* __restrict__ rs, const float* __restrict__ slots,
    const unsigned short* __restrict__ wihb, const unsigned short* __restrict__ whhb,
    const float* __restrict__ b_ih, const float* __restrict__ b_hh,
    float* __restrict__ gi, float* __restrict__ gh) {
  int x = blockIdx.x, y = blockIdx.y;
  const unsigned short* Wt = y ? whhb : wihb;
  const float* bias = y ? b_hh : b_ih;
  float* out = y ? gh : gi;
  int t = threadIdx.x, w = t >> 6, l = t & 63, lr = l & 15, lh = l >> 4;
  int col = x * 64 + w * 16 + lr;
  f32x4 acc[7];
#pragma unroll
  for (int m = 0; m < 7; m++) acc[m] = (f32x4){0.f, 0.f, 0.f, 0.f};
  for (int kk = 0; kk < 8; kk++) {
    int d0 = kk * 32 + lh * 8;
    bf16x8 b8 = *(const bf16x8*)(Wt + (size_t)col * 256 + d0);
    if (y) {
#pragma unroll
      for (int m = 0; m < 7; m++) {
        int row = m * 16 + lr;
        float4 h0 = *(const float4*)(slots + row * 256 + d0);
        float4 h1 = *(const float4*)(slots + row * 256 + d0 + 4);
        bf16x8 a;
        a[0] = (short)f2bf(h0.x); a[1] = (short)f2bf(h0.y);
        a[2] = (short)f2bf(h0.z); a[3] = (short)f2bf(h0.w);
        a[4] = (short)f2bf(h1.x); a[5] = (short)f2bf(h1.y);
        a[6] = (short)f2bf(h1.z); a[7] = (short)f2bf(h1.w);
        acc[m] = __builtin_amdgcn_mfma_f32_16x16x32_bf16(a, b8, acc[m], 0, 0, 0);
      }
    } else {
      float4 vs0 = *(const float4*)(vsum + d0);
      float4 vs1 = *(const float4*)(vsum + d0 + 4);
#pragma unroll
      for (int m = 0; m < 7; m++) {
        int row = m * 16 + lr;
        float inv = 1.f / (rs[row] + EPS_S);
        float4 u0 = *(const float4*)(uraw + row * 256 + d0);
        float4 u1 = *(const float4*)(uraw + row * 256 + d0 + 4);
        bf16x8 a;
        a[0] = (short)f2bf((u0.x + 1e-8f * vs0.x) * inv);
        a[1] = (short)f2bf((u0.y + 1e-8f * vs0.y) * inv);
        a[2] = (short)f2bf((u0.z + 1e-8f * vs0.z) * inv);
        a[3] = (short)f2bf((u0.w + 1e-8f * vs0.w) * inv);
        a[4] = (short)f2bf((u1.x + 1e-8f * vs1.x) * inv);
        a[5] = (short)f2bf((u1.y + 1e-8f * vs1.y) * inv);
        a[6] = (short)f2bf((u1.z + 1e-8f * vs1.z) * inv);
        a[7] = (short)f2bf((u1.w + 1e-8f * vs1.w) * inv);
        acc[m] = __builtin_amdgcn_mfma_f32_16x16x32_bf16(a, b8, acc[m], 0, 0, 0);
      }
    }
  }
  float bb = bias[col];
#pragma unroll
  for (int m = 0; m < 7; m++)
#pragma unroll
    for (int r = 0; r < 4; r++)
      out[(size_t)(m * 16 + lh * 4 + r) * 768 + col] = acc[m][r] + bb;
}

// ============ LDS-staged coalesced per-row tail, fp8 weights (320KB/block) ============
#define WBUF_EL 8448  // bytes per ping-pong buffer

__device__ __forceinline__ void gemv8_g256(const unsigned char* __restrict__ W, int nchunks,
                                           const float* __restrict__ xl, float* __restrict__ outp,
                                           unsigned char* __restrict__ wbuf, int t) {
  __syncthreads();
  int s = t & 7, r = t >> 3;
  float xseg[32];
#pragma unroll
  for (int k = 0; k < 8; k++) *(float4*)&xseg[k * 4] = *(const float4*)&xl[s * 32 + k * 4];
  uint2 pf[4];
#pragma unroll
  for (int q = 0; q < 4; q++) pf[q] = *(const uint2*)(W + (size_t)(q * 256 + t) * 8);
  for (int n = 0; n < nchunks; n++) {
    unsigned char* buf = wbuf + (n & 1) * WBUF_EL;
#pragma unroll
    for (int q = 0; q < 4; q++) {
      int idx = q * 256 + t;
      *(uint2*)(buf + (idx >> 5) * 264 + (idx & 31) * 8) = pf[q];
    }
    if (n + 1 < nchunks) {
      const unsigned char* src = W + (size_t)(n + 1) * 8192;
#pragma unroll
      for (int q = 0; q < 4; q++) pf[q] = *(const uint2*)(src + (size_t)(q * 256 + t) * 8);
    }
    __syncthreads();
    const unsigned char* row = buf + r * 264 + s * 32;
    float acc = 0.f;
#pragma unroll
    for (int k8 = 0; k8 < 4; k8++) {
      uint2 a = *(const uint2*)(row + k8 * 8);
#pragma unroll
      for (int e = 0; e < 4; e++)
        acc += fp8d((unsigned char)((a.x >> (8 * e)) & 0xFF)) * xseg[k8 * 8 + e];
#pragma unroll
      for (int e = 0; e < 4; e++)
        acc += fp8d((unsigned char)((a.y >> (8 * e)) & 0xFF)) * xseg[k8 * 8 + 4 + e];
    }
    acc += __shfl_xor(acc, 1, 64);
    acc += __shfl_xor(acc, 2, 64);
    acc += __shfl_xor(acc, 4, 64);
    if (s == 0) outp[n * 32 + r] = acc;
  }
  __syncthreads();
}

__device__ __forceinline__ void gemv8_g512(const unsigned char* __restrict__ W, int nchunks,
                                           const float* __restrict__ xl, float* __restrict__ outp,
                                           unsigned char* __restrict__ wbuf, int t) {
  __syncthreads();
  int s = t & 15, r = t >> 4;
  float xseg[32];
#pragma unroll
  for (int k = 0; k < 8; k++) *(float4*)&xseg[k * 4] = *(const float4*)&xl[s * 32 + k * 4];
  uint2 pf[4];
#pragma unroll
  for (int q = 0; q < 4; q++) pf[q] = *(const uint2*)(W + (size_t)(q * 256 + t) * 8);
  for (int n = 0; n < nchunks; n++) {
    unsigned char* buf = wbuf + (n & 1) * WBUF_EL;
#pragma unroll
    for (int q = 0; q < 4; q++) {
      int idx = q * 256 + t;
      *(uint2*)(buf + (idx >> 6) * 520 + (idx & 63) * 8) = pf[q];
    }
    if (n + 1 < nchunks) {
      const unsigned char* src = W + (size_t)(n + 1) * 8192;
#pragma unroll
      for (int q = 0; q < 4; q++) pf[q] = *(const uint2*)(src + (size_t)(q * 256 + t) * 8);
    }
    __syncthreads();
    const unsigned char* row = buf + r * 520 + s * 32;
    float acc = 0.f;
#pragma unroll
    for (int k8 = 0; k8 < 4; k8++) {
      uint2 a = *(const uint2*)(row + k8 * 8);
#pragma unroll
      for (int e = 0; e < 4; e++)
        acc += fp8d((unsigned char)((a.x >> (8 * e)) & 0xFF)) * xseg[k8 * 8 + e];
#pragma unroll
      for (int e = 0; e < 4; e++)
        acc += fp8d((unsigned char)((a.y >> (8 * e)) & 0xFF)) * xseg[k8 * 8 + 4 + e];
    }
    acc += __shfl_xor(acc, 1, 64);
    acc += __shfl_xor(acc, 2, 64);
    acc += __shfl_xor(acc, 4, 64);
    acc += __shfl_xor(acc, 8, 64);
    if (s == 0) outp[n * 16 + r] = acc;
  }
  __syncthreads();
}

// one block per slot row: GRU elementwise (from gi/gh) + LN_ff + mlp1 + mlp2 + LN_sl + qproj
__global__ __launch_bounds__(256) void k_tail2(
    const float* __restrict__ gi, const float* __restrict__ gh,
    float* __restrict__ slots,
    const unsigned char* __restrict__ w1F8, const float* __restrict__ b1,
    const unsigned char* __restrict__ w2F8, const float* __restrict__ b2,
    const float* __restrict__ g_ff, const float* __restrict__ be_ff,
    const float* __restrict__ g_sl, const float* __restrict__ be_sl,
    const unsigned char* __restrict__ wqF8, const float* __restrict__ bq,
    unsigned short* __restrict__ qbf) {
  int i = blockIdx.x, t = threadIdx.x;
  __shared__ float u_l[256], h_l[256], shid[512];
  __shared__ float gacc[512];
  __shared__ unsigned char wbuf[2 * WBUF_EL];
  __shared__ float red[8];
  int wave = t >> 6, lane = t & 63;
  // GRU elementwise: gates already include biases (k_gates)
  float gA0 = gi[i * 768 + t], gA1 = gi[i * 768 + 256 + t], gA2 = gi[i * 768 + 512 + t];
  float gB0 = gh[i * 768 + t], gB1 = gh[i * 768 + 256 + t], gB2 = gh[i * 768 + 512 + t];
  float h = slots[i * 256 + t];
  float rg = 1.f / (1.f + __expf(-(gA0 + gB0)));
  float zg = 1.f / (1.f + __expf(-(gA1 + gB1)));
  float ng = tanhf(gA2 + rg * gB2);
  float ns_ = (1.f - zg) * ng + zg * h;
  // LN_ff -> u_l (x for mlp1)
  float s = allred_sum(ns_);
  if (lane == 0) red[wave] = s;
  __syncthreads();
  float mean = (red[0] + red[1] + red[2] + red[3]) * (1.f / 256.f);
  float dv = ns_ - mean;
  float s2 = allred_sum(dv * dv);
  if (lane == 0) red[4 + wave] = s2;
  __syncthreads();
  float var = (red[4] + red[5] + red[6] + red[7]) * (1.f / 256.f);
  u_l[t] = dv * rsqrtf(var + 1e-5f) * g_ff[t] + be_ff[t];
  // mlp1: 512 rows -> gacc[0..511]
  gemv8_g256(w1F8, 16, u_l, gacc, wbuf, t);
  shid[t] = fmaxf(gacc[t] + b1[t], 0.f);
  shid[t + 256] = fmaxf(gacc[t + 256] + b1[t + 256], 0.f);
  // mlp2: 256 rows, K=512 -> gacc[0..255]
  gemv8_g512(w2F8, 16, shid, gacc, wbuf, t);
  float o = ns_ + b2[t] + gacc[t];
  slots[i * 256 + t] = o;
  // LN_sl -> h_l (x for qproj)
  float s3 = allred_sum(o);
  if (lane == 0) red[wave] = s3;
  __syncthreads();
  float mean2 = (red[0] + red[1] + red[2] + red[3]) * (1.f / 256.f);
  float dv2 = o - mean2;
  float s4 = allred_sum(dv2 * dv2);
  if (lane == 0) red[4 + wave] = s4;
  __syncthreads();
  float var2 = (red[4] + red[5] + red[6] + red[7]) * (1.f / 256.f);
  h_l[t] = dv2 * rsqrtf(var2 + 1e-5f) * g_sl[t] + be_sl[t];
  // qproj: 256 rows -> gacc[0..255]
  gemv8_g256(wqF8, 8, h_l, gacc, wbuf, t);
  qbf[i * 256 + t] = f2bf(bq[t] + gacc[t]);
}

extern "C" void kernel_launch(void* const* d_in, const int* in_sizes, int n_in,
                              void* d_out, int out_size, void* d_ws, size_t ws_size,
                              hipStream_t stream) {
  const float* doc = (const float*)d_in[0];
  const float* w_wa = (const float*)d_in[3];
  const float* b_wa = (const float*)d_in[4];
  const float* wemb = (const float*)d_in[5];
  const float* wsp = (const float*)d_in[6];
  const float* bsp = (const float*)d_in[7];
  const float* slots_q = (const float*)d_in[8];
  const float* wq = (const float*)d_in[9];
  const float* bq = (const float*)d_in[10];
  const float* wk = (const float*)d_in[11];
  const float* bk = (const float*)d_in[12];
  const float* wv = (const float*)d_in[13];
  const float* bv = (const float*)d_in[14];
  const float* w_ih = (const float*)d_in[15];
  const float* w_hh = (const float*)d_in[16];
  const float* b_ih = (const float*)d_in[17];
  const float* b_hh = (const float*)d_in[18];
  const float* w1 = (const float*)d_in[19];
  const float* b1 = (const float*)d_in[20];
  const float* w2 = (const float*)d_in[21];
  const float* b2 = (const float*)d_in[22];
  const float* g_in = (const float*)d_in[23];
  const float* be_in = (const float*)d_in[24];
  const float* g_sl = (const float*)d_in[25];
  const float* be_sl = (const float*)d_in[26];
  const float* g_ff = (const float*)d_in[27];
  const float* be_ff = (const float*)d_in[28];

  const int S = S_TOT;
  float* out = (float*)d_out;
  float* coref = out;          // 100*S
  float* xin = out + 100 * S;  // S*256 (LN'd `inputs`)

  // f32 workspace (zero region [vsum, rowsum x3, uraw x3] must be contiguous)
  float* ws = (float*)d_ws;
  float* wa = ws;                 // 1024
  float* Wd = wa + 1024;          // 7680
  float* A = Wd + 7680;           // 262144
  float* Bm = A + 262144;         // 262144
  float* Cm = Bm + 262144;        // 262144
  float* vsum = Cm + 262144;      // 256   <- zero region start (86656 floats)
  float* rowsum = vsum + 256;     // 3*128
  float* uraw = rowsum + 384;     // 3*28672
  float* slots = uraw + 86016;    // 112*256
  float* gi = slots + 28672;      // 112*768
  float* gh = gi + 86016;         // 112*768
  // bf16 workspace
  unsigned short* ub = (unsigned short*)(gh + 86016);
  unsigned short* inb = ub;                           // SPAD*256
  unsigned short* kbuf = inb + (size_t)SPAD * 256;    // SPAD*256
  unsigned short* vT = kbuf + (size_t)SPAD * 256;     // 256*SPAD
  unsigned short* pT = vT + (size_t)SPAD * 256;       // 112*SPAD
  unsigned short* qbf = pT + (size_t)112 * SPAD;      // 112*256
  unsigned short* docb = qbf + 112 * 256;             // 1024*1024
  unsigned short* wspT = docb + 1024 * 1024;          // 768*1024
  unsigned short* wkT = wspT + 768 * 1024;            // 256*256
  unsigned short* wvT = wkT + 256 * 256;              // 256*256
  unsigned short* wqT = wvT + 256 * 256;              // 256*256
  unsigned short* wihb = wqT + 256 * 256;             // 768*256
  unsigned short* whhb = wihb + 768 * 256;            // 768*256
  unsigned short* w1T = whhb + 768 * 256;             // 512*256
  unsigned short* w2T = w1T + 512 * 256;              // 256*512
  // fp8 workspace
  unsigned char* wqF8 = (unsigned char*)(w2T + 256 * 512);  // 256*256
  unsigned char* w1F8 = wqF8 + 256 * 256;                   // 512*256
  unsigned char* w2F8 = w1F8 + 512 * 256;                   // 256*512

  k_prep<<<8049, 256, 0, stream>>>(doc, w_wa, b_wa, wemb, wsp, wk, wv, wq, w1, w2,
                                   w_ih, w_hh, slots_q, wa, Wd, docb, wihb, whhb, wspT,
                                   wkT, wvT, wqT, w1T, w2T, wqF8, w1F8, w2F8, slots, vsum,
                                   inb + (size_t)S * 256);
  k_abc_mfma<<<dim3(16, 3), 256, 0, stream>>>(docb, wspT, A, Bm, Cm);
  k_spans_ln<<<1024, 256, 0, stream>>>(wa, A, Bm, Cm, Wd, bsp, g_in, be_in, xin, inb);
  k_kv_mfma<<<SPAD / 64, 256, 0, stream>>>(inb, wkT, wvT, bk, bv, kbuf, vT, vsum);
  k_qln0<<<112, 256, 0, stream>>>(slots, g_sl, be_sl, wqT, bq, qbf);

  for (int it = 0; it < 3; ++it) {
    float* rs_it = rowsum + it * 128;
    float* uraw_it = uraw + it * 28672;
    k_dots_f<<<SPAD / 64, 256, 0, stream>>>(kbuf, qbf, pT, rs_it, coref, 0, S);
    k_upd_mfma<<<dim3(96, 2), 256, 0, stream>>>(pT, vT, uraw_it);
    k_gates<<<dim3(12, 2), 256, 0, stream>>>(uraw_it, vsum, rs_it, slots, wihb, whhb,
                                             b_ih, b_hh, gi, gh);
    k_tail2<<<100, 256, 0, stream>>>(gi, gh, slots, w1F8, b1, w2F8, b2, g_ff, be_ff,
                                     g_sl, be_sl, wqF8, bq, qbf);
  }
  k_dots_f<<<SPAD / 64, 256, 0, stream>>>(kbuf, qbf, pT, rowsum, coref, 1, S);
}

// Round 17
// 396.765 us; speedup vs baseline: 1.2667x; 1.2667x over previous
//
#include <hip/hip_runtime.h>

#define S_TOT 30285
#define SPAD  30720
#define EPS_S 3.0285e-4f  // 1e-8 * S_TOT

typedef __attribute__((ext_vector_type(8))) short bf16x8;
typedef __attribute__((ext_vector_type(4))) float f32x4;

__device__ __forceinline__ unsigned short f2bf(float f) {
  unsigned u = __float_as_uint(f);
  u += 0x7FFFu + ((u >> 16) & 1u);
  return (unsigned short)(u >> 16);
}
__device__ __forceinline__ float bf2f(unsigned short h) {
  return __uint_as_float(((unsigned)h) << 16);
}
__device__ __forceinline__ float allred_sum(float v) {
#pragma unroll
  for (int o = 32; o > 0; o >>= 1) v += __shfl_xor(v, o, 64);
  return v;
}

// ---------- fused prep: word_attn + wd + casts + transposes + slot init + zeroing ----------
__global__ void k_prep(const float* __restrict__ doc, const float* __restrict__ w_wa,
                       const float* __restrict__ b_wa, const float* __restrict__ wemb,
                       const float* __restrict__ wsp, const float* __restrict__ wk,
                       const float* __restrict__ wv, const float* __restrict__ wq,
                       const float* __restrict__ w1, const float* __restrict__ w2,
                       const float* __restrict__ wih, const float* __restrict__ whh,
                       const float* __restrict__ slots_q, float* __restrict__ wa,
                       float* __restrict__ Wd, unsigned short* __restrict__ docb,
                       unsigned short* __restrict__ wihb, unsigned short* __restrict__ whhb,
                       unsigned short* __restrict__ wspT, unsigned short* __restrict__ wkT,
                       unsigned short* __restrict__ wvT, unsigned short* __restrict__ wqT,
                       unsigned short* __restrict__ w1T, unsigned short* __restrict__ w2T,
                       float* __restrict__ slots, float* __restrict__ zeroF,
                       unsigned short* __restrict__ inbpad) {
  __shared__ float shf[1056];
  int b = blockIdx.x, t = threadIdx.x;
  if (b < 1024) {  // word_attn
    float s = 0.f;
    for (int h = t; h < 1024; h += 256) s += doc[b * 1024 + h] * w_wa[h];
    shf[t] = s;
    __syncthreads();
    for (int o = 128; o; o >>= 1) {
      if (t < o) shf[t] += shf[t + o];
      __syncthreads();
    }
    if (t == 0) wa[b] = shf[0] + b_wa[0];
  } else if (b < 1054) {  // Wd
    int w = b - 1024;
    float s = 0.f;
    for (int j = 0; j < 20; j++) s += wemb[w * 20 + j] * wsp[(2048 + j) * 256 + t];
    Wd[w * 256 + t] = s;
  } else if (b < 6686) {  // row-major casts
    int b2 = b - 1054;
    if (b2 < 4096) { int i = b2 * 256 + t; docb[i] = f2bf(doc[i]); }
    else if (b2 < 4864) { int i = (b2 - 4096) * 256 + t; wihb[i] = f2bf(wih[i]); }
    else { int i = (b2 - 4864) * 256 + t; whhb[i] = f2bf(whh[i]); }
  } else if (b < 7902) {  // transposed casts
    int bb = b - 6686;
    const float* src; unsigned short* dst; int R, C, tid;
    if (bb < 768) {
      int sec = bb >> 8; tid = bb & 255;
      src = wsp + (sec == 0 ? 0 : (sec == 1 ? 1024 * 256 : 2068 * 256));
      dst = wspT + (size_t)sec * 256 * 1024; R = 1024; C = 256;
    } else if (bb < 832) { src = wk; dst = wkT; R = 256; C = 256; tid = bb - 768; }
    else if (bb < 896) { src = wv; dst = wvT; R = 256; C = 256; tid = bb - 832; }
    else if (bb < 960) { src = wq; dst = wqT; R = 256; C = 256; tid = bb - 896; }
    else if (bb < 1088) { src = w1; dst = w1T; R = 256; C = 512; tid = bb - 960; }
    else { src = w2; dst = w2T; R = 512; C = 256; tid = bb - 1088; }
    int cw = C >> 5;
    int c0 = (tid % cw) * 32, r0 = (tid / cw) * 32;
#pragma unroll
    for (int i = 0; i < 4; i++) {
      int e = i * 256 + t, rr = e >> 5, cc = e & 31;
      shf[rr * 33 + cc] = src[(size_t)(r0 + rr) * C + c0 + cc];
    }
    __syncthreads();
#pragma unroll
    for (int i = 0; i < 4; i++) {
      int e = i * 256 + t, cc = e >> 5, rr = e & 31;
      dst[(size_t)(c0 + cc) * R + r0 + rr] = f2bf(shf[rr * 33 + cc]);
    }
  } else if (b < 7909) {  // slots init (rows 0..99 copy, 100..111 zero)
    int r0 = (b - 7902) * 16;
    for (int rr = 0; rr < 16; rr++) {
      int row = r0 + rr;
      slots[row * 256 + t] = (row < 100) ? slots_q[row * 256 + t] : 0.f;
    }
  } else if (b < 7994) {  // zero f32 region: vsum(256) + rowsum(384) + uraw(86016)
    int i4 = (b - 7909) * 256 + t;
    if (i4 < 21664) ((float4*)zeroF)[i4] = (float4){0.f, 0.f, 0.f, 0.f};
  } else {  // zero inb padding rows (bf16)
    int i = (b - 7994) * 256 + t;
    if (i < 13920) ((uint4*)inbpad)[i] = (uint4){0u, 0u, 0u, 0u};
  }
}

// ---------- A/B/C projections (MFMA) ----------
__global__ __launch_bounds__(256) void k_abc_mfma(const unsigned short* __restrict__ docb,
                                                  const unsigned short* __restrict__ wspT,
                                                  float* __restrict__ A, float* __restrict__ B,
                                                  float* __restrict__ C) {
  int rt = blockIdx.x, sec = blockIdx.y;
  float* out = sec == 0 ? A : (sec == 1 ? B : C);
  const unsigned short* wt = wspT + (size_t)sec * 256 * 1024;
  __shared__ unsigned short lds[64 * 256];
  int t = threadIdx.x, w = t >> 6, l = t & 63, lr = l & 15, lh = l >> 4;
  f32x4 acc[4][4];
#pragma unroll
  for (int m = 0; m < 4; m++)
#pragma unroll
    for (int n = 0; n < 4; n++) acc[m][n] = (f32x4){0.f, 0.f, 0.f, 0.f};
  for (int kt = 0; kt < 4; kt++) {
    __syncthreads();
#pragma unroll
    for (int it = 0; it < 8; it++) {
      int e = it * 256 + t, row = e >> 5, c16 = e & 31;
      int ba = ((row * 512) + c16 * 16) ^ ((row & 7) << 4);
      *(uint4*)((char*)lds + ba) =
          *(const uint4*)(docb + (size_t)(rt * 64 + row) * 1024 + kt * 256 + c16 * 8);
    }
    __syncthreads();
    for (int kk = 0; kk < 8; kk++) {
      bf16x8 afr[4];
#pragma unroll
      for (int m = 0; m < 4; m++) {
        int row = m * 16 + lr;
        int ba = ((row * 512) + kk * 64 + lh * 16) ^ ((row & 7) << 4);
        afr[m] = *(bf16x8*)((char*)lds + ba);
      }
#pragma unroll
      for (int n = 0; n < 4; n++) {
        bf16x8 b8 = *(const bf16x8*)(wt + (size_t)(w * 64 + n * 16 + lr) * 1024 + kt * 256 +
                                     kk * 32 + lh * 8);
#pragma unroll
        for (int m = 0; m < 4; m++)
          acc[m][n] = __builtin_amdgcn_mfma_f32_16x16x32_bf16(afr[m], b8, acc[m][n], 0, 0, 0);
      }
    }
  }
#pragma unroll
  for (int n = 0; n < 4; n++) {
    int col = w * 64 + n * 16 + lr;
#pragma unroll
    for (int m = 0; m < 4; m++)
#pragma unroll
      for (int r = 0; r < 4; r++)
        out[(size_t)(rt * 64 + m * 16 + lh * 4 + r) * 256 + col] = acc[m][n][r];
  }
}

// ---------- spans: wave-parallel online-softmax + fused LN; no in-loop barriers ----------
__global__ void k_spans_ln(const float* __restrict__ wa, const float* __restrict__ A,
                           const float* __restrict__ B, const float* __restrict__ C,
                           const float* __restrict__ Wd, const float* __restrict__ bias,
                           const float* __restrict__ g_in, const float* __restrict__ be_in,
                           float* __restrict__ xin, unsigned short* __restrict__ inb) {
  int ss = blockIdx.x, t = threadIdx.x;
  int w = t >> 6, lane = t & 63;
  int nsp = min(30, 1024 - ss);
  int base = (ss < 995) ? ss * 30 : 29850 + 435 - ((1024 - ss) * (1025 - ss)) / 2;
  __shared__ float C_l[30 * 256];
  __shared__ float wa_l[30];
  for (int e = t; e < nsp * 256; e += 256)
    C_l[e] = C[(ss + (e >> 8)) * 256 + (e & 255)];
  if (t < nsp) wa_l[t] = wa[ss + t];
  __syncthreads();
  int c0 = lane * 4;
  float4 aS = *(const float4*)(A + ss * 256 + c0);
  float4 bi = *(const float4*)(bias + c0);
  float a0 = aS.x + bi.x, a1 = aS.y + bi.y, a2 = aS.z + bi.z, a3 = aS.w + bi.w;
  float4 gg = *(const float4*)(g_in + c0);
  float4 bb = *(const float4*)(be_in + c0);
  float m = -3.4e38f, Z = 0.f;
  float W0 = 0.f, W1 = 0.f, W2 = 0.f, W3 = 0.f;
  int pos = 0;
  for (int sp = w; sp < nsp; sp += 4) {
    for (; pos <= sp; ++pos) {
      float as_ = wa_l[pos];
      float mn = fmaxf(m, as_);
      float corr = __expf(m - mn);
      float e = __expf(as_ - mn);
      Z = Z * corr + e;
      float4 cc = *(const float4*)(C_l + pos * 256 + c0);
      W0 = W0 * corr + e * cc.x;
      W1 = W1 * corr + e * cc.y;
      W2 = W2 * corr + e * cc.z;
      W3 = W3 * corr + e * cc.w;
      m = mn;
    }
    float invZ = 1.f / Z;
    float4 Bv = *(const float4*)(B + (size_t)(ss + sp) * 256 + c0);
    float4 wd = *(const float4*)(Wd + sp * 256 + c0);
    float v0 = a0 + Bv.x + wd.x + W0 * invZ;
    float v1 = a1 + Bv.y + wd.y + W1 * invZ;
    float v2 = a2 + Bv.z + wd.z + W2 * invZ;
    float v3 = a3 + Bv.w + wd.w + W3 * invZ;
    float s = allred_sum(v0 + v1 + v2 + v3);
    float mean = s * (1.f / 256.f);
    float d0 = v0 - mean, d1 = v1 - mean, d2 = v2 - mean, d3 = v3 - mean;
    float q = allred_sum(d0 * d0 + d1 * d1 + d2 * d2 + d3 * d3);
    float rstd = rsqrtf(q * (1.f / 256.f) + 1e-5f);
    float o0 = d0 * rstd * gg.x + bb.x;
    float o1 = d1 * rstd * gg.y + bb.y;
    float o2 = d2 * rstd * gg.z + bb.z;
    float o3 = d3 * rstd * gg.w + bb.w;
    size_t r = (size_t)(base + sp) * 256 + c0;
    *(float4*)(xin + r) = (float4){o0, o1, o2, o3};
    ushort4 u4;
    u4.x = f2bf(o0); u4.y = f2bf(o1); u4.z = f2bf(o2); u4.w = f2bf(o3);
    *(ushort4*)(inb + r) = u4;
  }
}

// ---------- k/v projection MFMA; vsum fused; vT written via LDS transpose (coalesced) ----
__global__ __launch_bounds__(256) void k_kv_mfma(const unsigned short* __restrict__ inb,
                                                 const unsigned short* __restrict__ wkT,
                                                 const unsigned short* __restrict__ wvT,
                                                 const float* __restrict__ bk,
                                                 const float* __restrict__ bv,
                                                 unsigned short* __restrict__ kb,
                                                 unsigned short* __restrict__ vT,
                                                 float* __restrict__ vsum) {
  int j0 = blockIdx.x * 64;
  int t = threadIdx.x, w = t >> 6, l = t & 63, lr = l & 15, lh = l >> 4;
  __shared__ unsigned short lds[256 * 66];  // staging (first 32KB) then [col][row] v-tile
#pragma unroll
  for (int it = 0; it < 8; it++) {
    int e = it * 256 + t, row = e >> 5, c16 = e & 31;
    int ba = ((row * 512) + c16 * 16) ^ ((row & 7) << 4);
    *(uint4*)((char*)lds + ba) = *(const uint4*)(inb + (size_t)(j0 + row) * 256 + c16 * 8);
  }
  __syncthreads();
  f32x4 ak[4][4], av[4][4];
#pragma unroll
  for (int m = 0; m < 4; m++)
#pragma unroll
    for (int n = 0; n < 4; n++) {
      ak[m][n] = (f32x4){0.f, 0.f, 0.f, 0.f};
      av[m][n] = (f32x4){0.f, 0.f, 0.f, 0.f};
    }
  for (int kk = 0; kk < 8; kk++) {
    bf16x8 afr[4];
#pragma unroll
    for (int m = 0; m < 4; m++) {
      int row = m * 16 + lr;
      int ba = ((row * 512) + kk * 64 + lh * 16) ^ ((row & 7) << 4);
      afr[m] = *(bf16x8*)((char*)lds + ba);
    }
#pragma unroll
    for (int n = 0; n < 4; n++) {
      int col = w * 64 + n * 16 + lr;
      bf16x8 bk8 = *(const bf16x8*)(wkT + (size_t)col * 256 + kk * 32 + lh * 8);
      bf16x8 bv8 = *(const bf16x8*)(wvT + (size_t)col * 256 + kk * 32 + lh * 8);
#pragma unroll
      for (int m = 0; m < 4; m++) {
        ak[m][n] = __builtin_amdgcn_mfma_f32_16x16x32_bf16(afr[m], bk8, ak[m][n], 0, 0, 0);
        av[m][n] = __builtin_amdgcn_mfma_f32_16x16x32_bf16(afr[m], bv8, av[m][n], 0, 0, 0);
      }
    }
  }
  __syncthreads();  // all LDS staging reads done; safe to reuse lds for v transpose
#pragma unroll
  for (int n = 0; n < 4; n++) {
    int col = w * 64 + n * 16 + lr;
    float bks = bk[col], bvs = bv[col];
    float cs = 0.f;
#pragma unroll
    for (int m = 0; m < 4; m++)
#pragma unroll
      for (int r = 0; r < 4; r++) {
        int lrow = m * 16 + lh * 4 + r;
        int row = j0 + lrow;
        float kvv = ak[m][n][r] + bks;
        float vvv = av[m][n][r] + bvs;
        kb[(size_t)row * 256 + col] = f2bf(kvv);
        lds[col * 66 + lrow] = f2bf(vvv);
        if (row < S_TOT) cs += vvv;
      }
    cs += __shfl_xor(cs, 16, 64);
    cs += __shfl_xor(cs, 32, 64);
    if (lh == 0) atomicAdd(&vsum[col], cs);
  }
  __syncthreads();
  // coalesced vT writeout: wave w owns cols [w*64, w*64+64); lane l -> row l (128B runs)
  for (int cc = 0; cc < 64; cc++) {
    int col = w * 64 + cc;
    vT[(size_t)col * SPAD + j0 + l] = lds[col * 66 + l];
  }
}

// ---------- initial q: q = LN(slots)@wq + bq (one block per slot row, VALU) ----------
__global__ void k_qln0(const float* __restrict__ slots, const float* __restrict__ g_sl,
                       const float* __restrict__ be_sl, const unsigned short* __restrict__ wqT,
                       const float* __restrict__ bq, unsigned short* __restrict__ qbf) {
  int i = blockIdx.x, t = threadIdx.x;
  if (i >= 100) { qbf[i * 256 + t] = 0; return; }
  __shared__ float ln_l[256];
  __shared__ float red[8];
  int wave = t >> 6, lane = t & 63;
  float v = slots[i * 256 + t];
  float s = allred_sum(v);
  if (lane == 0) red[wave] = s;
  __syncthreads();
  float mean = (red[0] + red[1] + red[2] + red[3]) * (1.f / 256.f);
  float dv = v - mean;
  float s2 = allred_sum(dv * dv);
  if (lane == 0) red[4 + wave] = s2;
  __syncthreads();
  float var = (red[4] + red[5] + red[6] + red[7]) * (1.f / 256.f);
  ln_l[t] = dv * rsqrtf(var + 1e-5f) * g_sl[t] + be_sl[t];
  __syncthreads();
  float q = bq[t];
  size_t c = (size_t)t * 256;
  for (int d = 0; d < 256; d += 8) {
    bf16x8 a = *(const bf16x8*)(wqT + c + d);
#pragma unroll
    for (int e = 0; e < 8; e++) q += bf2f((unsigned short)a[e]) * ln_l[d + e];
  }
  qbf[i * 256 + t] = f2bf(q);
}

// ---------- fused dots(MFMA) + slot-softmax + (pT/rowsum | coref) ----------
__global__ __launch_bounds__(256) void k_dots_f(const unsigned short* __restrict__ kb,
                                                const unsigned short* __restrict__ qb,
                                                unsigned short* __restrict__ pT,
                                                float* __restrict__ rowsum,
                                                float* __restrict__ coref, int final_, int S_) {
  int j0 = blockIdx.x * 64;
  int t = threadIdx.x, w = t >> 6, l = t & 63, lr = l & 15, lh = l >> 4;
  f32x4 acc[7];
#pragma unroll
  for (int n = 0; n < 7; n++) acc[n] = (f32x4){0.f, 0.f, 0.f, 0.f};
  const unsigned short* arow = kb + (size_t)(j0 + w * 16 + lr) * 256;
  for (int kk = 0; kk < 8; kk++) {
    bf16x8 a8 = *(const bf16x8*)(arow + kk * 32 + lh * 8);
#pragma unroll
    for (int n = 0; n < 7; n++) {
      bf16x8 b8 = *(const bf16x8*)(qb + (size_t)(n * 16 + lr) * 256 + kk * 32 + lh * 8);
      acc[n] = __builtin_amdgcn_mfma_f32_16x16x32_bf16(a8, b8, acc[n], 0, 0, 0);
    }
  }
  __shared__ float dt[64][117];
#pragma unroll
  for (int n = 0; n < 7; n++)
#pragma unroll
    for (int r = 0; r < 4; r++) dt[w * 16 + lh * 4 + r][n * 16 + lr] = acc[n][r] * 0.0625f;
  __syncthreads();
  int jj = t >> 2, q4 = t & 3;
  float mx = -3.4e38f;
#pragma unroll
  for (int i = 0; i < 25; i++) mx = fmaxf(mx, dt[jj][q4 * 25 + i]);
  mx = fmaxf(mx, __shfl_xor(mx, 1, 64));
  mx = fmaxf(mx, __shfl_xor(mx, 2, 64));
  float sm = 0.f;
#pragma unroll
  for (int i = 0; i < 25; i++) {
    float e = __expf(dt[jj][q4 * 25 + i] - mx);
    dt[jj][q4 * 25 + i] = e;
    sm += e;
  }
  sm += __shfl_xor(sm, 1, 64);
  sm += __shfl_xor(sm, 2, 64);
  float inv = 1.f / sm;
#pragma unroll
  for (int i = 0; i < 25; i++) dt[jj][q4 * 25 + i] *= inv;
  __syncthreads();
  if (!final_) {
    for (int e = t; e < 112 * 64; e += 256) {
      int i = e >> 6, j2 = e & 63;
      float pv = (i < 100 && (j0 + j2) < S_) ? dt[j2][i] : 0.f;
      pT[(size_t)i * SPAD + j0 + j2] = f2bf(pv);
    }
    int nv = S_ - j0;
    if (nv > 64) nv = 64;
    if (t < 100) {
      float s = 0.f;
      for (int j2 = 0; j2 < nv; j2++) s += dt[j2][t];
      atomicAdd(rowsum + t, s);
    }
  } else {
    for (int e = t; e < 100 * 64; e += 256) {
      int i = e >> 6, j2 = e & 63;
      if ((j0 + j2) < S_) coref[(size_t)i * S_ + j0 + j2] = fminf(dt[j2][i] + 1e-8f, 1.0f);
    }
  }
}

// ---------- updates: uraw += pT @ v (MFMA split-K atomics) ----------
__global__ __launch_bounds__(256) void k_upd_mfma(const unsigned short* __restrict__ pT,
                                                  const unsigned short* __restrict__ vT,
                                                  float* __restrict__ uraw) {
  int kc = blockIdx.x, ny = blockIdx.y;
  int t = threadIdx.x, w = t >> 6, l = t & 63, lr = l & 15, lh = l >> 4;
  int k0 = kc * 320;
  int c0 = ny * 128 + w * 32;
  f32x4 acc[7][2];
#pragma unroll
  for (int m = 0; m < 7; m++) {
    acc[m][0] = (f32x4){0.f, 0.f, 0.f, 0.f};
    acc[m][1] = (f32x4){0.f, 0.f, 0.f, 0.f};
  }
  for (int ks = 0; ks < 10; ks++) {
    int kof = k0 + ks * 32 + lh * 8;
    bf16x8 b0 = *(const bf16x8*)(vT + (size_t)(c0 + lr) * SPAD + kof);
    bf16x8 b1 = *(const bf16x8*)(vT + (size_t)(c0 + 16 + lr) * SPAD + kof);
#pragma unroll
    for (int m = 0; m < 7; m++) {
      bf16x8 a8 = *(const bf16x8*)(pT + (size_t)(m * 16 + lr) * SPAD + kof);
      acc[m][0] = __builtin_amdgcn_mfma_f32_16x16x32_bf16(a8, b0, acc[m][0], 0, 0, 0);
      acc[m][1] = __builtin_amdgcn_mfma_f32_16x16x32_bf16(a8, b1, acc[m][1], 0, 0, 0);
    }
  }
#pragma unroll
  for (int m = 0; m < 7; m++)
#pragma unroll
    for (int n = 0; n < 2; n++)
#pragma unroll
      for (int r = 0; r < 4; r++) {
        int i = m * 16 + lh * 4 + r;
        if (i < 100) atomicAdd(&uraw[i * 256 + c0 + n * 16 + lr], acc[m][n][r]);
      }
}

// ---------- gates GEMM (col-tiled, 24 blocks): gi/gh = {u,slots}@W^T + b ----------
__global__ __launch_bounds__(256) void k_gates(
    const float* __restrict__ uraw, const float* __restrict__ vsum,
    const float* __restrict__ rs, const float* __restrict__ slots,
    const unsigned short* __restrict__ wihb, const unsigned short* __restrict__ whhb,
    const float* __restrict__ b_ih, const float* __restrict__ b_hh,
    float* __restrict__ gi, float* __restrict__ gh) {
  int x = blockIdx.x, y = blockIdx.y;
  const unsigned short* Wt = y ? whhb : wihb;
  const float* bias = y ? b_hh : b_ih;
  float* out = y ? gh : gi;
  int t = threadIdx.x, w = t >> 6, l = t & 63, lr = l & 15, lh = l >> 4;
  int col = x * 64 + w * 16 + lr;
  f32x4 acc[7];
#pragma unroll
  for (int m = 0; m < 7; m++) acc[m] = (f32x4){0.f, 0.f, 0.f, 0.f};
  for (int kk = 0; kk < 8; kk++) {
    int d0 = kk * 32 + lh * 8;
    bf16x8 b8 = *(const bf16x8*)(Wt + (size_t)col * 256 + d0);
    if (y) {
#pragma unroll
      for (int m = 0; m < 7; m++) {
        int row = m * 16 + lr;
        float4 h0 = *(const float4*)(slots + row * 256 + d0);
        float4 h1 = *(const float4*)(slots + row * 256 + d0 + 4);
        bf16x8 a;
        a[0] = (short)f2bf(h0.x); a[1] = (short)f2bf(h0.y);
        a[2] = (short)f2bf(h0.z); a[3] = (short)f2bf(h0.w);
        a[4] = (short)f2bf(h1.x); a[5] = (short)f2bf(h1.y);
        a[6] = (short)f2bf(h1.z); a[7] = (short)f2bf(h1.w);
        acc[m] = __builtin_amdgcn_mfma_f32_16x16x32_bf16(a, b8, acc[m], 0, 0, 0);
      }
    } else {
      float4 vs0 = *(const float4*)(vsum + d0);
      float4 vs1 = *(const float4*)(vsum + d0 + 4);
#pragma unroll
      for (int m = 0; m < 7; m++) {
        int row = m * 16 + lr;
        float inv = 1.f / (rs[row] + EPS_S);
        float4 u0 = *(const float4*)(uraw + row * 256 + d0);
        float4 u1 = *(const float4*)(uraw + row * 256 + d0 + 4);
        bf16x8 a;
        a[0] = (short)f2bf((u0.x + 1e-8f * vs0.x) * inv);
        a[1] = (short)f2bf((u0.y + 1e-8f * vs0.y) * inv);
        a[2] = (short)f2bf((u0.z + 1e-8f * vs0.z) * inv);
        a[3] = (short)f2bf((u0.w + 1e-8f * vs0.w) * inv);
        a[4] = (short)f2bf((u1.x + 1e-8f * vs1.x) * inv);
        a[5] = (short)f2bf((u1.y + 1e-8f * vs1.y) * inv);
        a[6] = (short)f2bf((u1.z + 1e-8f * vs1.z) * inv);
        a[7] = (short)f2bf((u1.w + 1e-8f * vs1.w) * inv);
        acc[m] = __builtin_amdgcn_mfma_f32_16x16x32_bf16(a, b8, acc[m], 0, 0, 0);
      }
    }
  }
  float bb = bias[col];
#pragma unroll
  for (int m = 0; m < 7; m++)
#pragma unroll
    for (int r = 0; r < 4; r++)
      out[(size_t)(m * 16 + lh * 4 + r) * 768 + col] = acc[m][r] + bb;
}

// ================= LDS-staged coalesced per-row tail (weights 640KB/block) ==============
#define WBUF_EL 8448

__device__ __forceinline__ void gemv_g256(const unsigned short* __restrict__ W, int nchunks,
                                          const float* __restrict__ xl, float* __restrict__ outp,
                                          unsigned short* __restrict__ wbuf, int t) {
  __syncthreads();
  int s = t & 7, r = t >> 3;
  float xseg[32];
#pragma unroll
  for (int k = 0; k < 8; k++) *(float4*)&xseg[k * 4] = *(const float4*)&xl[s * 32 + k * 4];
  bf16x8 pf[4];
#pragma unroll
  for (int q = 0; q < 4; q++) pf[q] = *(const bf16x8*)(W + (size_t)(q * 256 + t) * 8);
  for (int n = 0; n < nchunks; n++) {
    unsigned short* buf = wbuf + (n & 1) * WBUF_EL;
#pragma unroll
    for (int q = 0; q < 4; q++) {
      int idx = q * 256 + t;
      *(bf16x8*)(buf + (idx >> 5) * 264 + (idx & 31) * 8) = pf[q];
    }
    if (n + 1 < nchunks) {
      const unsigned short* src = W + (size_t)(n + 1) * 8192;
#pragma unroll
      for (int q = 0; q < 4; q++) pf[q] = *(const bf16x8*)(src + (size_t)(q * 256 + t) * 8);
    }
    __syncthreads();
    const unsigned short* row = wbuf + (n & 1) * WBUF_EL + r * 264 + s * 32;
    float acc = 0.f;
#pragma unroll
    for (int k8 = 0; k8 < 4; k8++) {
      bf16x8 a = *(const bf16x8*)(row + k8 * 8);
#pragma unroll
      for (int e = 0; e < 8; e++) acc += bf2f((unsigned short)a[e]) * xseg[k8 * 8 + e];
    }
    acc += __shfl_xor(acc, 1, 64);
    acc += __shfl_xor(acc, 2, 64);
    acc += __shfl_xor(acc, 4, 64);
    if (s == 0) outp[n * 32 + r] = acc;
  }
  __syncthreads();
}

__device__ __forceinline__ void gemv_g512(const unsigned short* __restrict__ W, int nchunks,
                                          const float* __restrict__ xl, float* __restrict__ outp,
                                          unsigned short* __restrict__ wbuf, int t) {
  __syncthreads();
  int s = t & 15, r = t >> 4;
  float xseg[32];
#pragma unroll
  for (int k = 0; k < 8; k++) *(float4*)&xseg[k * 4] = *(const float4*)&xl[s * 32 + k * 4];
  bf16x8 pf[4];
#pragma unroll
  for (int q = 0; q < 4; q++) pf[q] = *(const bf16x8*)(W + (size_t)(q * 256 + t) * 8);
  for (int n = 0; n < nchunks; n++) {
    unsigned short* buf = wbuf + (n & 1) * WBUF_EL;
#pragma unroll
    for (int q = 0; q < 4; q++) {
      int idx = q * 256 + t;
      *(bf16x8*)(buf + (idx >> 6) * 520 + (idx & 63) * 8) = pf[q];
    }
    if (n + 1 < nchunks) {
      const unsigned short* src = W + (size_t)(n + 1) * 8192;
#pragma unroll
      for (int q = 0; q < 4; q++) pf[q] = *(const bf16x8*)(src + (size_t)(q * 256 + t) * 8);
    }
    __syncthreads();
    const unsigned short* row = wbuf + (n & 1) * WBUF_EL + r * 520 + s * 32;
    float acc = 0.f;
#pragma unroll
    for (int k8 = 0; k8 < 4; k8++) {
      bf16x8 a = *(const bf16x8*)(row + k8 * 8);
#pragma unroll
      for (int e = 0; e < 8; e++) acc += bf2f((unsigned short)a[e]) * xseg[k8 * 8 + e];
    }
    acc += __shfl_xor(acc, 1, 64);
    acc += __shfl_xor(acc, 2, 64);
    acc += __shfl_xor(acc, 4, 64);
    acc += __shfl_xor(acc, 8, 64);
    if (s == 0) outp[n * 16 + r] = acc;
  }
  __syncthreads();
}

// one block per slot row: GRU elementwise (from gi/gh) + LN_ff + mlp1 + mlp2 + LN_sl + qproj
__global__ __launch_bounds__(256) void k_tail2(
    const float* __restrict__ gi, const float* __restrict__ gh,
    float* __restrict__ slots,
    const unsigned short* __restrict__ w1T, const float* __restrict__ b1,
    const unsigned short* __restrict__ w2T, const float* __restrict__ b2,
    const float* __restrict__ g_ff, const float* __restrict__ be_ff,
    const float* __restrict__ g_sl, const float* __restrict__ be_sl,
    const unsigned short* __restrict__ wqT, const float* __restrict__ bq,
    unsigned short* __restrict__ qbf) {
  int i = blockIdx.x, t = threadIdx.x;
  __shared__ float u_l[256], h_l[256], shid[512];
  __shared__ float gacc[512];
  __shared__ unsigned short wbuf[2 * WBUF_EL];
  __shared__ float red[8];
  int wave = t >> 6, lane = t & 63;
  // GRU elementwise: gates already include biases (k_gates)
  float gA0 = gi[i * 768 + t], gA1 = gi[i * 768 + 256 + t], gA2 = gi[i * 768 + 512 + t];
  float gB0 = gh[i * 768 + t], gB1 = gh[i * 768 + 256 + t], gB2 = gh[i * 768 + 512 + t];
  float h = slots[i * 256 + t];
  float rg = 1.f / (1.f + __expf(-(gA0 + gB0)));
  float zg = 1.f / (1.f + __expf(-(gA1 + gB1)));
  float ng = tanhf(gA2 + rg * gB2);
  float ns_ = (1.f - zg) * ng + zg * h;
  // LN_ff -> u_l (x for mlp1)
  float s = allred_sum(ns_);
  if (lane == 0) red[wave] = s;
  __syncthreads();
  float mean = (red[0] + red[1] + red[2] + red[3]) * (1.f / 256.f);
  float dv = ns_ - mean;
  float s2 = allred_sum(dv * dv);
  if (lane == 0) red[4 + wave] = s2;
  __syncthreads();
  float var = (red[4] + red[5] + red[6] + red[7]) * (1.f / 256.f);
  u_l[t] = dv * rsqrtf(var + 1e-5f) * g_ff[t] + be_ff[t];
  // mlp1: 512 rows -> gacc[0..511]
  gemv_g256(w1T, 16, u_l, gacc, wbuf, t);
  shid[t] = fmaxf(gacc[t] + b1[t], 0.f);
  shid[t + 256] = fmaxf(gacc[t + 256] + b1[t + 256], 0.f);
  // mlp2: 256 rows, K=512 -> gacc[0..255]
  gemv_g512(w2T, 16, shid, gacc, wbuf, t);
  float o = ns_ + b2[t] + gacc[t];
  slots[i * 256 + t] = o;
  // LN_sl -> h_l (x for qproj)
  float s3 = allred_sum(o);
  if (lane == 0) red[wave] = s3;
  __syncthreads();
  float mean2 = (red[0] + red[1] + red[2] + red[3]) * (1.f / 256.f);
  float dv2 = o - mean2;
  float s4 = allred_sum(dv2 * dv2);
  if (lane == 0) red[4 + wave] = s4;
  __syncthreads();
  float var2 = (red[4] + red[5] + red[6] + red[7]) * (1.f / 256.f);
  h_l[t] = dv2 * rsqrtf(var2 + 1e-5f) * g_sl[t] + be_sl[t];
  // qproj: 256 rows -> gacc[0..255]
  gemv_g256(wqT, 8, h_l, gacc, wbuf, t);
  qbf[i * 256 + t] = f2bf(bq[t] + gacc[t]);
}

extern "C" void kernel_launch(void* const* d_in, const int* in_sizes, int n_in,
                              void* d_out, int out_size, void* d_ws, size_t ws_size,
                              hipStream_t stream) {
  const float* doc = (const float*)d_in[0];
  const float* w_wa = (const float*)d_in[3];
  const float* b_wa = (const float*)d_in[4];
  const float* wemb = (const float*)d_in[5];
  const float* wsp = (const float*)d_in[6];
  const float* bsp = (const float*)d_in[7];
  const float* slots_q = (const float*)d_in[8];
  const float* wq = (const float*)d_in[9];
  const float* bq = (const float*)d_in[10];
  const float* wk = (const float*)d_in[11];
  const float* bk = (const float*)d_in[12];
  const float* wv = (const float*)d_in[13];
  const float* bv = (const float*)d_in[14];
  const float* w_ih = (const float*)d_in[15];
  const float* w_hh = (const float*)d_in[16];
  const float* b_ih = (const float*)d_in[17];
  const float* b_hh = (const float*)d_in[18];
  const float* w1 = (const float*)d_in[19];
  const float* b1 = (const float*)d_in[20];
  const float* w2 = (const float*)d_in[21];
  const float* b2 = (const float*)d_in[22];
  const float* g_in = (const float*)d_in[23];
  const float* be_in = (const float*)d_in[24];
  const float* g_sl = (const float*)d_in[25];
  const float* be_sl = (const float*)d_in[26];
  const float* g_ff = (const float*)d_in[27];
  const float* be_ff = (const float*)d_in[28];

  const int S = S_TOT;
  float* out = (float*)d_out;
  float* coref = out;          // 100*S
  float* xin = out + 100 * S;  // S*256 (LN'd `inputs`)

  // f32 workspace (zero region [vsum, rowsum x3, uraw x3] must be contiguous)
  float* ws = (float*)d_ws;
  float* wa = ws;                 // 1024
  float* Wd = wa + 1024;          // 7680
  float* A = Wd + 7680;           // 262144
  float* Bm = A + 262144;         // 262144
  float* Cm = Bm + 262144;        // 262144
  float* vsum = Cm + 262144;      // 256   <- zero region start (86656 floats)
  float* rowsum = vsum + 256;     // 3*128
  float* uraw = rowsum + 384;     // 3*28672
  float* slots = uraw + 86016;    // 112*256
  float* gi = slots + 28672;      // 112*768
  float* gh = gi + 86016;         // 112*768
  // bf16 workspace
  unsigned short* ub = (unsigned short*)(gh + 86016);
  unsigned short* inb = ub;                           // SPAD*256
  unsigned short* kbuf = inb + (size_t)SPAD * 256;    // SPAD*256
  unsigned short* vT = kbuf + (size_t)SPAD * 256;     // 256*SPAD
  unsigned short* pT = vT + (size_t)SPAD * 256;       // 112*SPAD
  unsigned short* qbf = pT + (size_t)112 * SPAD;      // 112*256
  unsigned short* docb = qbf + 112 * 256;             // 1024*1024
  unsigned short* wspT = docb + 1024 * 1024;          // 768*1024
  unsigned short* wkT = wspT + 768 * 1024;            // 256*256
  unsigned short* wvT = wkT + 256 * 256;              // 256*256
  unsigned short* wqT = wvT + 256 * 256;              // 256*256
  unsigned short* wihb = wqT + 256 * 256;             // 768*256
  unsigned short* whhb = wihb + 768 * 256;            // 768*256
  unsigned short* w1T = whhb + 768 * 256;             // 512*256
  unsigned short* w2T = w1T + 512 * 256;              // 256*512

  k_prep<<<8049, 256, 0, stream>>>(doc, w_wa, b_wa, wemb, wsp, wk, wv, wq, w1, w2,
                                   w_ih, w_hh, slots_q, wa, Wd, docb, wihb, whhb, wspT,
                                   wkT, wvT, wqT, w1T, w2T, slots, vsum,
                                   inb + (size_t)S * 256);
  k_abc_mfma<<<dim3(16, 3), 256, 0, stream>>>(docb, wspT, A, Bm, Cm);
  k_spans_ln<<<1024, 256, 0, stream>>>(wa, A, Bm, Cm, Wd, bsp, g_in, be_in, xin, inb);
  k_kv_mfma<<<SPAD / 64, 256, 0, stream>>>(inb, wkT, wvT, bk, bv, kbuf, vT, vsum);
  k_qln0<<<112, 256, 0, stream>>>(slots, g_sl, be_sl, wqT, bq, qbf);

  for (int it = 0; it < 3; ++it) {
    float* rs_it = rowsum + it * 128;
    float* uraw_it = uraw + it * 28672;
    k_dots_f<<<SPAD / 64, 256, 0, stream>>>(kbuf, qbf, pT, rs_it, coref, 0, S);
    k_upd_mfma<<<dim3(96, 2), 256, 0, stream>>>(pT, vT, uraw_it);
    k_gates<<<dim3(12, 2), 256, 0, stream>>>(uraw_it, vsum, rs_it, slots, wihb, whhb,
                                             b_ih, b_hh, gi, gh);
    k_tail2<<<100, 256, 0, stream>>>(gi, gh, slots, w1T, b1, w2T, b2, g_ff, be_ff,
                                     g_sl, be_sl, wqT, bq, qbf);
  }
  k_dots_f<<<SPAD / 64, 256, 0, stream>>>(kbuf, qbf, pT, rowsum, coref, 1, S);
}

// Round 18
// 392.764 us; speedup vs baseline: 1.2796x; 1.0102x over previous
//
#include <hip/hip_runtime.h>

#define S_TOT 30285
#define SPAD  30720
#define EPS_S 3.0285e-4f  // 1e-8 * S_TOT

typedef __attribute__((ext_vector_type(8))) short bf16x8;
typedef __attribute__((ext_vector_type(4))) float f32x4;

__device__ __forceinline__ unsigned short f2bf(float f) {
  unsigned u = __float_as_uint(f);
  u += 0x7FFFu + ((u >> 16) & 1u);
  return (unsigned short)(u >> 16);
}
__device__ __forceinline__ float bf2f(unsigned short h) {
  return __uint_as_float(((unsigned)h) << 16);
}
__device__ __forceinline__ float allred_sum(float v) {
#pragma unroll
  for (int o = 32; o > 0; o >>= 1) v += __shfl_xor(v, o, 64);
  return v;
}

// ---------- fused prep: word_attn + wd + casts + transposes + slot init + zeroing ----------
__global__ void k_prep(const float* __restrict__ doc, const float* __restrict__ w_wa,
                       const float* __restrict__ b_wa, const float* __restrict__ wemb,
                       const float* __restrict__ wsp, const float* __restrict__ wk,
                       const float* __restrict__ wv, const float* __restrict__ wq,
                       const float* __restrict__ w1, const float* __restrict__ w2,
                       const float* __restrict__ wih, const float* __restrict__ whh,
                       const float* __restrict__ slots_q, float* __restrict__ wa,
                       float* __restrict__ Wd, unsigned short* __restrict__ docb,
                       unsigned short* __restrict__ wihb, unsigned short* __restrict__ whhb,
                       unsigned short* __restrict__ wspT, unsigned short* __restrict__ wkT,
                       unsigned short* __restrict__ wvT, unsigned short* __restrict__ wqT,
                       unsigned short* __restrict__ w1T, unsigned short* __restrict__ w2T,
                       float* __restrict__ slots, float* __restrict__ zeroF,
                       unsigned short* __restrict__ inbpad) {
  __shared__ float shf[1056];
  int b = blockIdx.x, t = threadIdx.x;
  if (b < 1024) {  // word_attn
    float s = 0.f;
    for (int h = t; h < 1024; h += 256) s += doc[b * 1024 + h] * w_wa[h];
    shf[t] = s;
    __syncthreads();
    for (int o = 128; o; o >>= 1) {
      if (t < o) shf[t] += shf[t + o];
      __syncthreads();
    }
    if (t == 0) wa[b] = shf[0] + b_wa[0];
  } else if (b < 1054) {  // Wd
    int w = b - 1024;
    float s = 0.f;
    for (int j = 0; j < 20; j++) s += wemb[w * 20 + j] * wsp[(2048 + j) * 256 + t];
    Wd[w * 256 + t] = s;
  } else if (b < 6686) {  // row-major casts
    int b2 = b - 1054;
    if (b2 < 4096) { int i = b2 * 256 + t; docb[i] = f2bf(doc[i]); }
    else if (b2 < 4864) { int i = (b2 - 4096) * 256 + t; wihb[i] = f2bf(wih[i]); }
    else { int i = (b2 - 4864) * 256 + t; whhb[i] = f2bf(whh[i]); }
  } else if (b < 7902) {  // transposed casts
    int bb = b - 6686;
    const float* src; unsigned short* dst; int R, C, tid;
    if (bb < 768) {
      int sec = bb >> 8; tid = bb & 255;
      src = wsp + (sec == 0 ? 0 : (sec == 1 ? 1024 * 256 : 2068 * 256));
      dst = wspT + (size_t)sec * 256 * 1024; R = 1024; C = 256;
    } else if (bb < 832) { src = wk; dst = wkT; R = 256; C = 256; tid = bb - 768; }
    else if (bb < 896) { src = wv; dst = wvT; R = 256; C = 256; tid = bb - 832; }
    else if (bb < 960) { src = wq; dst = wqT; R = 256; C = 256; tid = bb - 896; }
    else if (bb < 1088) { src = w1; dst = w1T; R = 256; C = 512; tid = bb - 960; }
    else { src = w2; dst = w2T; R = 512; C = 256; tid = bb - 1088; }
    int cw = C >> 5;
    int c0 = (tid % cw) * 32, r0 = (tid / cw) * 32;
#pragma unroll
    for (int i = 0; i < 4; i++) {
      int e = i * 256 + t, rr = e >> 5, cc = e & 31;
      shf[rr * 33 + cc] = src[(size_t)(r0 + rr) * C + c0 + cc];
    }
    __syncthreads();
#pragma unroll
    for (int i = 0; i < 4; i++) {
      int e = i * 256 + t, cc = e >> 5, rr = e & 31;
      dst[(size_t)(c0 + cc) * R + r0 + rr] = f2bf(shf[rr * 33 + cc]);
    }
  } else if (b < 7909) {  // slots init (rows 0..99 copy, 100..111 zero)
    int r0 = (b - 7902) * 16;
    for (int rr = 0; rr < 16; rr++) {
      int row = r0 + rr;
      slots[row * 256 + t] = (row < 100) ? slots_q[row * 256 + t] : 0.f;
    }
  } else if (b < 7994) {  // zero f32 region: vsum(256) + rowsum(384) + uraw(86016)
    int i4 = (b - 7909) * 256 + t;
    if (i4 < 21664) ((float4*)zeroF)[i4] = (float4){0.f, 0.f, 0.f, 0.f};
  } else {  // zero inb padding rows (bf16)
    int i = (b - 7994) * 256 + t;
    if (i < 13920) ((uint4*)inbpad)[i] = (uint4){0u, 0u, 0u, 0u};
  }
}

// ---------- A/B/C projections (MFMA) ----------
__global__ __launch_bounds__(256) void k_abc_mfma(const unsigned short* __restrict__ docb,
                                                  const unsigned short* __restrict__ wspT,
                                                  float* __restrict__ A, float* __restrict__ B,
                                                  float* __restrict__ C) {
  int rt = blockIdx.x, sec = blockIdx.y;
  float* out = sec == 0 ? A : (sec == 1 ? B : C);
  const unsigned short* wt = wspT + (size_t)sec * 256 * 1024;
  __shared__ unsigned short lds[64 * 256];
  int t = threadIdx.x, w = t >> 6, l = t & 63, lr = l & 15, lh = l >> 4;
  f32x4 acc[4][4];
#pragma unroll
  for (int m = 0; m < 4; m++)
#pragma unroll
    for (int n = 0; n < 4; n++) acc[m][n] = (f32x4){0.f, 0.f, 0.f, 0.f};
  for (int kt = 0; kt < 4; kt++) {
    __syncthreads();
#pragma unroll
    for (int it = 0; it < 8; it++) {
      int e = it * 256 + t, row = e >> 5, c16 = e & 31;
      int ba = ((row * 512) + c16 * 16) ^ ((row & 7) << 4);
      *(uint4*)((char*)lds + ba) =
          *(const uint4*)(docb + (size_t)(rt * 64 + row) * 1024 + kt * 256 + c16 * 8);
    }
    __syncthreads();
    for (int kk = 0; kk < 8; kk++) {
      bf16x8 afr[4];
#pragma unroll
      for (int m = 0; m < 4; m++) {
        int row = m * 16 + lr;
        int ba = ((row * 512) + kk * 64 + lh * 16) ^ ((row & 7) << 4);
        afr[m] = *(bf16x8*)((char*)lds + ba);
      }
#pragma unroll
      for (int n = 0; n < 4; n++) {
        bf16x8 b8 = *(const bf16x8*)(wt + (size_t)(w * 64 + n * 16 + lr) * 1024 + kt * 256 +
                                     kk * 32 + lh * 8);
#pragma unroll
        for (int m = 0; m < 4; m++)
          acc[m][n] = __builtin_amdgcn_mfma_f32_16x16x32_bf16(afr[m], b8, acc[m][n], 0, 0, 0);
      }
    }
  }
#pragma unroll
  for (int n = 0; n < 4; n++) {
    int col = w * 64 + n * 16 + lr;
#pragma unroll
    for (int m = 0; m < 4; m++)
#pragma unroll
      for (int r = 0; r < 4; r++)
        out[(size_t)(rt * 64 + m * 16 + lh * 4 + r) * 256 + col] = acc[m][n][r];
  }
}

// ---------- spans: wave-parallel online-softmax + fused LN; no in-loop barriers ----------
__global__ void k_spans_ln(const float* __restrict__ wa, const float* __restrict__ A,
                           const float* __restrict__ B, const float* __restrict__ C,
                           const float* __restrict__ Wd, const float* __restrict__ bias,
                           const float* __restrict__ g_in, const float* __restrict__ be_in,
                           float* __restrict__ xin, unsigned short* __restrict__ inb) {
  int ss = blockIdx.x, t = threadIdx.x;
  int w = t >> 6, lane = t & 63;
  int nsp = min(30, 1024 - ss);
  int base = (ss < 995) ? ss * 30 : 29850 + 435 - ((1024 - ss) * (1025 - ss)) / 2;
  __shared__ float C_l[30 * 256];
  __shared__ float wa_l[30];
  for (int e = t; e < nsp * 256; e += 256)
    C_l[e] = C[(ss + (e >> 8)) * 256 + (e & 255)];
  if (t < nsp) wa_l[t] = wa[ss + t];
  __syncthreads();
  int c0 = lane * 4;
  float4 aS = *(const float4*)(A + ss * 256 + c0);
  float4 bi = *(const float4*)(bias + c0);
  float a0 = aS.x + bi.x, a1 = aS.y + bi.y, a2 = aS.z + bi.z, a3 = aS.w + bi.w;
  float4 gg = *(const float4*)(g_in + c0);
  float4 bb = *(const float4*)(be_in + c0);
  float m = -3.4e38f, Z = 0.f;
  float W0 = 0.f, W1 = 0.f, W2 = 0.f, W3 = 0.f;
  int pos = 0;
  for (int sp = w; sp < nsp; sp += 4) {
    for (; pos <= sp; ++pos) {
      float as_ = wa_l[pos];
      float mn = fmaxf(m, as_);
      float corr = __expf(m - mn);
      float e = __expf(as_ - mn);
      Z = Z * corr + e;
      float4 cc = *(const float4*)(C_l + pos * 256 + c0);
      W0 = W0 * corr + e * cc.x;
      W1 = W1 * corr + e * cc.y;
      W2 = W2 * corr + e * cc.z;
      W3 = W3 * corr + e * cc.w;
      m = mn;
    }
    float invZ = 1.f / Z;
    float4 Bv = *(const float4*)(B + (size_t)(ss + sp) * 256 + c0);
    float4 wd = *(const float4*)(Wd + sp * 256 + c0);
    float v0 = a0 + Bv.x + wd.x + W0 * invZ;
    float v1 = a1 + Bv.y + wd.y + W1 * invZ;
    float v2 = a2 + Bv.z + wd.z + W2 * invZ;
    float v3 = a3 + Bv.w + wd.w + W3 * invZ;
    float s = allred_sum(v0 + v1 + v2 + v3);
    float mean = s * (1.f / 256.f);
    float d0 = v0 - mean, d1 = v1 - mean, d2 = v2 - mean, d3 = v3 - mean;
    float q = allred_sum(d0 * d0 + d1 * d1 + d2 * d2 + d3 * d3);
    float rstd = rsqrtf(q * (1.f / 256.f) + 1e-5f);
    float o0 = d0 * rstd * gg.x + bb.x;
    float o1 = d1 * rstd * gg.y + bb.y;
    float o2 = d2 * rstd * gg.z + bb.z;
    float o3 = d3 * rstd * gg.w + bb.w;
    size_t r = (size_t)(base + sp) * 256 + c0;
    *(float4*)(xin + r) = (float4){o0, o1, o2, o3};
    ushort4 u4;
    u4.x = f2bf(o0); u4.y = f2bf(o1); u4.z = f2bf(o2); u4.w = f2bf(o3);
    *(ushort4*)(inb + r) = u4;
  }
}

// ---------- k/v projection MFMA; vsum fused ----------
__global__ __launch_bounds__(256) void k_kv_mfma(const unsigned short* __restrict__ inb,
                                                 const unsigned short* __restrict__ wkT,
                                                 const unsigned short* __restrict__ wvT,
                                                 const float* __restrict__ bk,
                                                 const float* __restrict__ bv,
                                                 unsigned short* __restrict__ kb,
                                                 unsigned short* __restrict__ vT,
                                                 float* __restrict__ vsum) {
  int j0 = blockIdx.x * 64;
  int t = threadIdx.x, w = t >> 6, l = t & 63, lr = l & 15, lh = l >> 4;
  __shared__ unsigned short lds[64 * 256];
#pragma unroll
  for (int it = 0; it < 8; it++) {
    int e = it * 256 + t, row = e >> 5, c16 = e & 31;
    int ba = ((row * 512) + c16 * 16) ^ ((row & 7) << 4);
    *(uint4*)((char*)lds + ba) = *(const uint4*)(inb + (size_t)(j0 + row) * 256 + c16 * 8);
  }
  __syncthreads();
  f32x4 ak[4][4], av[4][4];
#pragma unroll
  for (int m = 0; m < 4; m++)
#pragma unroll
    for (int n = 0; n < 4; n++) {
      ak[m][n] = (f32x4){0.f, 0.f, 0.f, 0.f};
      av[m][n] = (f32x4){0.f, 0.f, 0.f, 0.f};
    }
  for (int kk = 0; kk < 8; kk++) {
    bf16x8 afr[4];
#pragma unroll
    for (int m = 0; m < 4; m++) {
      int row = m * 16 + lr;
      int ba = ((row * 512) + kk * 64 + lh * 16) ^ ((row & 7) << 4);
      afr[m] = *(bf16x8*)((char*)lds + ba);
    }
#pragma unroll
    for (int n = 0; n < 4; n++) {
      int col = w * 64 + n * 16 + lr;
      bf16x8 bk8 = *(const bf16x8*)(wkT + (size_t)col * 256 + kk * 32 + lh * 8);
      bf16x8 bv8 = *(const bf16x8*)(wvT + (size_t)col * 256 + kk * 32 + lh * 8);
#pragma unroll
      for (int m = 0; m < 4; m++) {
        ak[m][n] = __builtin_amdgcn_mfma_f32_16x16x32_bf16(afr[m], bk8, ak[m][n], 0, 0, 0);
        av[m][n] = __builtin_amdgcn_mfma_f32_16x16x32_bf16(afr[m], bv8, av[m][n], 0, 0, 0);
      }
    }
  }
#pragma unroll
  for (int n = 0; n < 4; n++) {
    int col = w * 64 + n * 16 + lr;
    float bks = bk[col], bvs = bv[col];
    float cs = 0.f;
#pragma unroll
    for (int m = 0; m < 4; m++)
#pragma unroll
      for (int r = 0; r < 4; r++) {
        int row = j0 + m * 16 + lh * 4 + r;
        float kvv = ak[m][n][r] + bks;
        float vvv = av[m][n][r] + bvs;
        kb[(size_t)row * 256 + col] = f2bf(kvv);
        vT[(size_t)col * SPAD + row] = f2bf(vvv);
        if (row < S_TOT) cs += vvv;
      }
    cs += __shfl_xor(cs, 16, 64);
    cs += __shfl_xor(cs, 32, 64);
    if (lh == 0) atomicAdd(&vsum[col], cs);
  }
}

// ---------- initial q: q = LN(slots)@wq + bq (one block per slot row, VALU) ----------
__global__ void k_qln0(const float* __restrict__ slots, const float* __restrict__ g_sl,
                       const float* __restrict__ be_sl, const unsigned short* __restrict__ wqT,
                       const float* __restrict__ bq, unsigned short* __restrict__ qbf) {
  int i = blockIdx.x, t = threadIdx.x;
  if (i >= 100) { qbf[i * 256 + t] = 0; return; }
  __shared__ float ln_l[256];
  __shared__ float red[8];
  int wave = t >> 6, lane = t & 63;
  float v = slots[i * 256 + t];
  float s = allred_sum(v);
  if (lane == 0) red[wave] = s;
  __syncthreads();
  float mean = (red[0] + red[1] + red[2] + red[3]) * (1.f / 256.f);
  float dv = v - mean;
  float s2 = allred_sum(dv * dv);
  if (lane == 0) red[4 + wave] = s2;
  __syncthreads();
  float var = (red[4] + red[5] + red[6] + red[7]) * (1.f / 256.f);
  ln_l[t] = dv * rsqrtf(var + 1e-5f) * g_sl[t] + be_sl[t];
  __syncthreads();
  float q = bq[t];
  size_t c = (size_t)t * 256;
  for (int d = 0; d < 256; d += 8) {
    bf16x8 a = *(const bf16x8*)(wqT + c + d);
#pragma unroll
    for (int e = 0; e < 8; e++) q += bf2f((unsigned short)a[e]) * ln_l[d + e];
  }
  qbf[i * 256 + t] = f2bf(q);
}

// ---------- fused dots(MFMA) + slot-softmax + (pT/rowsum | coref) ----------
__global__ __launch_bounds__(256) void k_dots_f(const unsigned short* __restrict__ kb,
                                                const unsigned short* __restrict__ qb,
                                                unsigned short* __restrict__ pT,
                                                float* __restrict__ rowsum,
                                                float* __restrict__ coref, int final_, int S_) {
  int j0 = blockIdx.x * 64;
  int t = threadIdx.x, w = t >> 6, l = t & 63, lr = l & 15, lh = l >> 4;
  f32x4 acc[7];
#pragma unroll
  for (int n = 0; n < 7; n++) acc[n] = (f32x4){0.f, 0.f, 0.f, 0.f};
  const unsigned short* arow = kb + (size_t)(j0 + w * 16 + lr) * 256;
  for (int kk = 0; kk < 8; kk++) {
    bf16x8 a8 = *(const bf16x8*)(arow + kk * 32 + lh * 8);
#pragma unroll
    for (int n = 0; n < 7; n++) {
      bf16x8 b8 = *(const bf16x8*)(qb + (size_t)(n * 16 + lr) * 256 + kk * 32 + lh * 8);
      acc[n] = __builtin_amdgcn_mfma_f32_16x16x32_bf16(a8, b8, acc[n], 0, 0, 0);
    }
  }
  __shared__ float dt[64][117];
#pragma unroll
  for (int n = 0; n < 7; n++)
#pragma unroll
    for (int r = 0; r < 4; r++) dt[w * 16 + lh * 4 + r][n * 16 + lr] = acc[n][r] * 0.0625f;
  __syncthreads();
  int jj = t >> 2, q4 = t & 3;
  float mx = -3.4e38f;
#pragma unroll
  for (int i = 0; i < 25; i++) mx = fmaxf(mx, dt[jj][q4 * 25 + i]);
  mx = fmaxf(mx, __shfl_xor(mx, 1, 64));
  mx = fmaxf(mx, __shfl_xor(mx, 2, 64));
  float sm = 0.f;
#pragma unroll
  for (int i = 0; i < 25; i++) {
    float e = __expf(dt[jj][q4 * 25 + i] - mx);
    dt[jj][q4 * 25 + i] = e;
    sm += e;
  }
  sm += __shfl_xor(sm, 1, 64);
  sm += __shfl_xor(sm, 2, 64);
  float inv = 1.f / sm;
#pragma unroll
  for (int i = 0; i < 25; i++) dt[jj][q4 * 25 + i] *= inv;
  __syncthreads();
  if (!final_) {
    for (int e = t; e < 112 * 64; e += 256) {
      int i = e >> 6, j2 = e & 63;
      float pv = (i < 100 && (j0 + j2) < S_) ? dt[j2][i] : 0.f;
      pT[(size_t)i * SPAD + j0 + j2] = f2bf(pv);
    }
    int nv = S_ - j0;
    if (nv > 64) nv = 64;
    if (t < 100) {
      float s = 0.f;
      for (int j2 = 0; j2 < nv; j2++) s += dt[j2][t];
      atomicAdd(rowsum + t, s);
    }
  } else {
    for (int e = t; e < 100 * 64; e += 256) {
      int i = e >> 6, j2 = e & 63;
      if ((j0 + j2) < S_) coref[(size_t)i * S_ + j0 + j2] = fminf(dt[j2][i] + 1e-8f, 1.0f);
    }
  }
}

// ---------- updates: uraw += pT @ v (MFMA split-K atomics) ----------
__global__ __launch_bounds__(256) void k_upd_mfma(const unsigned short* __restrict__ pT,
                                                  const unsigned short* __restrict__ vT,
                                                  float* __restrict__ uraw) {
  int kc = blockIdx.x, ny = blockIdx.y;
  int t = threadIdx.x, w = t >> 6, l = t & 63, lr = l & 15, lh = l >> 4;
  int k0 = kc * 320;
  int c0 = ny * 128 + w * 32;
  f32x4 acc[7][2];
#pragma unroll
  for (int m = 0; m < 7; m++) {
    acc[m][0] = (f32x4){0.f, 0.f, 0.f, 0.f};
    acc[m][1] = (f32x4){0.f, 0.f, 0.f, 0.f};
  }
  for (int ks = 0; ks < 10; ks++) {
    int kof = k0 + ks * 32 + lh * 8;
    bf16x8 b0 = *(const bf16x8*)(vT + (size_t)(c0 + lr) * SPAD + kof);
    bf16x8 b1 = *(const bf16x8*)(vT + (size_t)(c0 + 16 + lr) * SPAD + kof);
#pragma unroll
    for (int m = 0; m < 7; m++) {
      bf16x8 a8 = *(const bf16x8*)(pT + (size_t)(m * 16 + lr) * SPAD + kof);
      acc[m][0] = __builtin_amdgcn_mfma_f32_16x16x32_bf16(a8, b0, acc[m][0], 0, 0, 0);
      acc[m][1] = __builtin_amdgcn_mfma_f32_16x16x32_bf16(a8, b1, acc[m][1], 0, 0, 0);
    }
  }
#pragma unroll
  for (int m = 0; m < 7; m++)
#pragma unroll
    for (int n = 0; n < 2; n++)
#pragma unroll
      for (int r = 0; r < 4; r++) {
        int i = m * 16 + lh * 4 + r;
        if (i < 100) atomicAdd(&uraw[i * 256 + c0 + n * 16 + lr], acc[m][n][r]);
      }
}

// ---------- gates GEMM (col-tiled, 24 blocks): gi/gh = {u,slots}@W^T + b ----------
__global__ __launch_bounds__(256) void k_gates(
    const float* __restrict__ uraw, const float* __restrict__ vsum,
    const float* __restrict__ rs, const float* __restrict__ slots,
    const unsigned short* __restrict__ wihb, const unsigned short* __restrict__ whhb,
    const float* __restrict__ b_ih, const float* __restrict__ b_hh,
    float* __restrict__ gi, float* __restrict__ gh) {
  int x = blockIdx.x, y = blockIdx.y;
  const unsigned short* Wt = y ? whhb : wihb;
  const float* bias = y ? b_hh : b_ih;
  float* out = y ? gh : gi;
  int t = threadIdx.x, w = t >> 6, l = t & 63, lr = l & 15, lh = l >> 4;
  int col = x * 64 + w * 16 + lr;
  f32x4 acc[7];
#pragma unroll
  for (int m = 0; m < 7; m++) acc[m] = (f32x4){0.f, 0.f, 0.f, 0.f};
  for (int kk = 0; kk < 8; kk++) {
    int d0 = kk * 32 + lh * 8;
    bf16x8 b8 = *(const bf16x8*)(Wt + (size_t)col * 256 + d0);
    if (y) {
#pragma unroll
      for (int m = 0; m < 7; m++) {
        int row = m * 16 + lr;
        float4 h0 = *(const float4*)(slots + row * 256 + d0);
        float4 h1 = *(const float4*)(slots + row * 256 + d0 + 4);
        bf16x8 a;
        a[0] = (short)f2bf(h0.x); a[1] = (short)f2bf(h0.y);
        a[2] = (short)f2bf(h0.z); a[3] = (short)f2bf(h0.w);
        a[4] = (short)f2bf(h1.x); a[5] = (short)f2bf(h1.y);
        a[6] = (short)f2bf(h1.z); a[7] = (short)f2bf(h1.w);
        acc[m] = __builtin_amdgcn_mfma_f32_16x16x32_bf16(a, b8, acc[m], 0, 0, 0);
      }
    } else {
      float4 vs0 = *(const float4*)(vsum + d0);
      float4 vs1 = *(const float4*)(vsum + d0 + 4);
#pragma unroll
      for (int m = 0; m < 7; m++) {
        int row = m * 16 + lr;
        float inv = 1.f / (rs[row] + EPS_S);
        float4 u0 = *(const float4*)(uraw + row * 256 + d0);
        float4 u1 = *(const float4*)(uraw + row * 256 + d0 + 4);
        bf16x8 a;
        a[0] = (short)f2bf((u0.x + 1e-8f * vs0.x) * inv);
        a[1] = (short)f2bf((u0.y + 1e-8f * vs0.y) * inv);
        a[2] = (short)f2bf((u0.z + 1e-8f * vs0.z) * inv);
        a[3] = (short)f2bf((u0.w + 1e-8f * vs0.w) * inv);
        a[4] = (short)f2bf((u1.x + 1e-8f * vs1.x) * inv);
        a[5] = (short)f2bf((u1.y + 1e-8f * vs1.y) * inv);
        a[6] = (short)f2bf((u1.z + 1e-8f * vs1.z) * inv);
        a[7] = (short)f2bf((u1.w + 1e-8f * vs1.w) * inv);
        acc[m] = __builtin_amdgcn_mfma_f32_16x16x32_bf16(a, b8, acc[m], 0, 0, 0);
      }
    }
  }
  float bb = bias[col];
#pragma unroll
  for (int m = 0; m < 7; m++)
#pragma unroll
    for (int r = 0; r < 4; r++)
      out[(size_t)(m * 16 + lh * 4 + r) * 768 + col] = acc[m][r] + bb;
}

// ================= LDS-staged coalesced per-row tail (weights 640KB/block) ==============
#define WBUF_EL 8448

__device__ __forceinline__ void gemv_g256(const unsigned short* __restrict__ W, int nchunks,
                                          const float* __restrict__ xl, float* __restrict__ outp,
                                          unsigned short* __restrict__ wbuf, int t) {
  __syncthreads();
  int s = t & 7, r = t >> 3;
  float xseg[32];
#pragma unroll
  for (int k = 0; k < 8; k++) *(float4*)&xseg[k * 4] = *(const float4*)&xl[s * 32 + k * 4];
  bf16x8 pf[4];
#pragma unroll
  for (int q = 0; q < 4; q++) pf[q] = *(const bf16x8*)(W + (size_t)(q * 256 + t) * 8);
  for (int n = 0; n < nchunks; n++) {
    unsigned short* buf = wbuf + (n & 1) * WBUF_EL;
#pragma unroll
    for (int q = 0; q < 4; q++) {
      int idx = q * 256 + t;
      *(bf16x8*)(buf + (idx >> 5) * 264 + (idx & 31) * 8) = pf[q];
    }
    if (n + 1 < nchunks) {
      const unsigned short* src = W + (size_t)(n + 1) * 8192;
#pragma unroll
      for (int q = 0; q < 4; q++) pf[q] = *(const bf16x8*)(src + (size_t)(q * 256 + t) * 8);
    }
    __syncthreads();
    const unsigned short* row = wbuf + (n & 1) * WBUF_EL + r * 264 + s * 32;
    float acc = 0.f;
#pragma unroll
    for (int k8 = 0; k8 < 4; k8++) {
      bf16x8 a = *(const bf16x8*)(row + k8 * 8);
#pragma unroll
      for (int e = 0; e < 8; e++) acc += bf2f((unsigned short)a[e]) * xseg[k8 * 8 + e];
    }
    acc += __shfl_xor(acc, 1, 64);
    acc += __shfl_xor(acc, 2, 64);
    acc += __shfl_xor(acc, 4, 64);
    if (s == 0) outp[n * 32 + r] = acc;
  }
  __syncthreads();
}

__device__ __forceinline__ void gemv_g512(const unsigned short* __restrict__ W, int nchunks,
                                          const float* __restrict__ xl, float* __restrict__ outp,
                                          unsigned short* __restrict__ wbuf, int t) {
  __syncthreads();
  int s = t & 15, r = t >> 4;
  float xseg[32];
#pragma unroll
  for (int k = 0; k < 8; k++) *(float4*)&xseg[k * 4] = *(const float4*)&xl[s * 32 + k * 4];
  bf16x8 pf[4];
#pragma unroll
  for (int q = 0; q < 4; q++) pf[q] = *(const bf16x8*)(W + (size_t)(q * 256 + t) * 8);
  for (int n = 0; n < nchunks; n++) {
    unsigned short* buf = wbuf + (n & 1) * WBUF_EL;
#pragma unroll
    for (int q = 0; q < 4; q++) {
      int idx = q * 256 + t;
      *(bf16x8*)(buf + (idx >> 6) * 520 + (idx & 63) * 8) = pf[q];
    }
    if (n + 1 < nchunks) {
      const unsigned short* src = W + (size_t)(n + 1) * 8192;
#pragma unroll
      for (int q = 0; q < 4; q++) pf[q] = *(const bf16x8*)(src + (size_t)(q * 256 + t) * 8);
    }
    __syncthreads();
    const unsigned short* row = wbuf + (n & 1) * WBUF_EL + r * 520 + s * 32;
    float acc = 0.f;
#pragma unroll
    for (int k8 = 0; k8 < 4; k8++) {
      bf16x8 a = *(const bf16x8*)(row + k8 * 8);
#pragma unroll
      for (int e = 0; e < 8; e++) acc += bf2f((unsigned short)a[e]) * xseg[k8 * 8 + e];
    }
    acc += __shfl_xor(acc, 1, 64);
    acc += __shfl_xor(acc, 2, 64);
    acc += __shfl_xor(acc, 4, 64);
    acc += __shfl_xor(acc, 8, 64);
    if (s == 0) outp[n * 16 + r] = acc;
  }
  __syncthreads();
}

// one block per slot row: GRU elementwise (from gi/gh) + LN_ff + mlp1 + mlp2 + LN_sl + qproj
__global__ __launch_bounds__(256) void k_tail2(
    const float* __restrict__ gi, const float* __restrict__ gh,
    float* __restrict__ slots,
    const unsigned short* __restrict__ w1T, const float* __restrict__ b1,
    const unsigned short* __restrict__ w2T, const float* __restrict__ b2,
    const float* __restrict__ g_ff, const float* __restrict__ be_ff,
    const float* __restrict__ g_sl, const float* __restrict__ be_sl,
    const unsigned short* __restrict__ wqT, const float* __restrict__ bq,
    unsigned short* __restrict__ qbf) {
  int i = blockIdx.x, t = threadIdx.x;
  __shared__ float u_l[256], h_l[256], shid[512];
  __shared__ float gacc[512];
  __shared__ unsigned short wbuf[2 * WBUF_EL];
  __shared__ float red[8];
  int wave = t >> 6, lane = t & 63;
  // GRU elementwise: gates already include biases (k_gates)
  float gA0 = gi[i * 768 + t], gA1 = gi[i * 768 + 256 + t], gA2 = gi[i * 768 + 512 + t];
  float gB0 = gh[i * 768 + t], gB1 = gh[i * 768 + 256 + t], gB2 = gh[i * 768 + 512 + t];
  float h = slots[i * 256 + t];
  float rg = 1.f / (1.f + __expf(-(gA0 + gB0)));
  float zg = 1.f / (1.f + __expf(-(gA1 + gB1)));
  float ng = tanhf(gA2 + rg * gB2);
  float ns_ = (1.f - zg) * ng + zg * h;
  // LN_ff -> u_l (x for mlp1)
  float s = allred_sum(ns_);
  if (lane == 0) red[wave] = s;
  __syncthreads();
  float mean = (red[0] + red[1] + red[2] + red[3]) * (1.f / 256.f);
  float dv = ns_ - mean;
  float s2 = allred_sum(dv * dv);
  if (lane == 0) red[4 + wave] = s2;
  __syncthreads();
  float var = (red[4] + red[5] + red[6] + red[7]) * (1.f / 256.f);
  u_l[t] = dv * rsqrtf(var + 1e-5f) * g_ff[t] + be_ff[t];
  // mlp1: 512 rows -> gacc[0..511]
  gemv_g256(w1T, 16, u_l, gacc, wbuf, t);
  shid[t] = fmaxf(gacc[t] + b1[t], 0.f);
  shid[t + 256] = fmaxf(gacc[t + 256] + b1[t + 256], 0.f);
  // mlp2: 256 rows, K=512 -> gacc[0..255]
  gemv_g512(w2T, 16, shid, gacc, wbuf, t);
  float o = ns_ + b2[t] + gacc[t];
  slots[i * 256 + t] = o;
  // LN_sl -> h_l (x for qproj)
  float s3 = allred_sum(o);
  if (lane == 0) red[wave] = s3;
  __syncthreads();
  float mean2 = (red[0] + red[1] + red[2] + red[3]) * (1.f / 256.f);
  float dv2 = o - mean2;
  float s4 = allred_sum(dv2 * dv2);
  if (lane == 0) red[4 + wave] = s4;
  __syncthreads();
  float var2 = (red[4] + red[5] + red[6] + red[7]) * (1.f / 256.f);
  h_l[t] = dv2 * rsqrtf(var2 + 1e-5f) * g_sl[t] + be_sl[t];
  // qproj: 256 rows -> gacc[0..255]
  gemv_g256(wqT, 8, h_l, gacc, wbuf, t);
  qbf[i * 256 + t] = f2bf(bq[t] + gacc[t]);
}

extern "C" void kernel_launch(void* const* d_in, const int* in_sizes, int n_in,
                              void* d_out, int out_size, void* d_ws, size_t ws_size,
                              hipStream_t stream) {
  const float* doc = (const float*)d_in[0];
  const float* w_wa = (const float*)d_in[3];
  const float* b_wa = (const float*)d_in[4];
  const float* wemb = (const float*)d_in[5];
  const float* wsp = (const float*)d_in[6];
  const float* bsp = (const float*)d_in[7];
  const float* slots_q = (const float*)d_in[8];
  const float* wq = (const float*)d_in[9];
  const float* bq = (const float*)d_in[10];
  const float* wk = (const float*)d_in[11];
  const float* bk = (const float*)d_in[12];
  const float* wv = (const float*)d_in[13];
  const float* bv = (const float*)d_in[14];
  const float* w_ih = (const float*)d_in[15];
  const float* w_hh = (const float*)d_in[16];
  const float* b_ih = (const float*)d_in[17];
  const float* b_hh = (const float*)d_in[18];
  const float* w1 = (const float*)d_in[19];
  const float* b1 = (const float*)d_in[20];
  const float* w2 = (const float*)d_in[21];
  const float* b2 = (const float*)d_in[22];
  const float* g_in = (const float*)d_in[23];
  const float* be_in = (const float*)d_in[24];
  const float* g_sl = (const float*)d_in[25];
  const float* be_sl = (const float*)d_in[26];
  const float* g_ff = (const float*)d_in[27];
  const float* be_ff = (const float*)d_in[28];

  const int S = S_TOT;
  float* out = (float*)d_out;
  float* coref = out;          // 100*S
  float* xin = out + 100 * S;  // S*256 (LN'd `inputs`)

  // f32 workspace (zero region [vsum, rowsum x3, uraw x3] must be contiguous)
  float* ws = (float*)d_ws;
  float* wa = ws;                 // 1024
  float* Wd = wa + 1024;          // 7680
  float* A = Wd + 7680;           // 262144
  float* Bm = A + 262144;         // 262144
  float* Cm = Bm + 262144;        // 262144
  float* vsum = Cm + 262144;      // 256   <- zero region start (86656 floats)
  float* rowsum = vsum + 256;     // 3*128
  float* uraw = rowsum + 384;     // 3*28672
  float* slots = uraw + 86016;    // 112*256
  float* gi = slots + 28672;      // 112*768
  float* gh = gi + 86016;         // 112*768
  // bf16 workspace
  unsigned short* ub = (unsigned short*)(gh + 86016);
  unsigned short* inb = ub;                           // SPAD*256
  unsigned short* kbuf = inb + (size_t)SPAD * 256;    // SPAD*256
  unsigned short* vT = kbuf + (size_t)SPAD * 256;     // 256*SPAD
  unsigned short* pT = vT + (size_t)SPAD * 256;       // 112*SPAD
  unsigned short* qbf = pT + (size_t)112 * SPAD;      // 112*256
  unsigned short* docb = qbf + 112 * 256;             // 1024*1024
  unsigned short* wspT = docb + 1024 * 1024;          // 768*1024
  unsigned short* wkT = wspT + 768 * 1024;            // 256*256
  unsigned short* wvT = wkT + 256 * 256;              // 256*256
  unsigned short* wqT = wvT + 256 * 256;              // 256*256
  unsigned short* wihb = wqT + 256 * 256;             // 768*256
  unsigned short* whhb = wihb + 768 * 256;            // 768*256
  unsigned short* w1T = whhb + 768 * 256;             // 512*256
  unsigned short* w2T = w1T + 512 * 256;              // 256*512

  k_prep<<<8049, 256, 0, stream>>>(doc, w_wa, b_wa, wemb, wsp, wk, wv, wq, w1, w2,
                                   w_ih, w_hh, slots_q, wa, Wd, docb, wihb, whhb, wspT,
                                   wkT, wvT, wqT, w1T, w2T, slots, vsum,
                                   inb + (size_t)S * 256);
  k_abc_mfma<<<dim3(16, 3), 256, 0, stream>>>(docb, wspT, A, Bm, Cm);
  k_spans_ln<<<1024, 256, 0, stream>>>(wa, A, Bm, Cm, Wd, bsp, g_in, be_in, xin, inb);
  k_kv_mfma<<<SPAD / 64, 256, 0, stream>>>(inb, wkT, wvT, bk, bv, kbuf, vT, vsum);
  k_qln0<<<112, 256, 0, stream>>>(slots, g_sl, be_sl, wqT, bq, qbf);

  for (int it = 0; it < 3; ++it) {
    float* rs_it = rowsum + it * 128;
    float* uraw_it = uraw + it * 28672;
    k_dots_f<<<SPAD / 64, 256, 0, stream>>>(kbuf, qbf, pT, rs_it, coref, 0, S);
    k_upd_mfma<<<dim3(96, 2), 256, 0, stream>>>(pT, vT, uraw_it);
    k_gates<<<dim3(12, 2), 256, 0, stream>>>(uraw_it, vsum, rs_it, slots, wihb, whhb,
                                             b_ih, b_hh, gi, gh);
    k_tail2<<<100, 256, 0, stream>>>(gi, gh, slots, w1T, b1, w2T, b2, g_ff, be_ff,
                                     g_sl, be_sl, wqT, bq, qbf);
  }
  k_dots_f<<<SPAD / 64, 256, 0, stream>>>(kbuf, qbf, pT, rowsum, coref, 1, S);
}